// Round 1
// baseline (727.968 us; speedup 1.0000x reference)
//
#include <hip/hip_runtime.h>

// Problem constants (from reference)
#define N_NODES 100000
#define N_EDGES 1600000
#define D_IN    50
#define HIDDEN  128
#define NCLS    8

// ---------------------------------------------------------------------------
// Kernel 1: scatter x rows into aggx[dst] and count degree.
// 64 threads per edge (lanes 0..49 carry features; lane 0 also bumps degree).
// Reads of x[src] row are contiguous (200B); atomics land in L2/LLC.
// ---------------------------------------------------------------------------
__global__ __launch_bounds__(256) void scatter_x_deg(
    const float* __restrict__ x,
    const int*   __restrict__ src,
    const int*   __restrict__ dst,
    float* __restrict__ aggx,
    float* __restrict__ deg)
{
    int tid = blockIdx.x * 256 + threadIdx.x;
    int e = tid >> 6;
    int d = tid & 63;
    if (e >= N_EDGES) return;
    int s = src[e];
    int t = dst[e];
    if (d < D_IN) atomicAdd(&aggx[t * D_IN + d], x[s * D_IN + d]);
    if (d == 0)   atomicAdd(&deg[t], 1.0f);
}

// ---------------------------------------------------------------------------
// Kernel 2: fused layer-1 GEMM: h = relu(aggx/deg @ W1_l + x @ W1_r + b1)
// W1_l, W1_r staged once per block in LDS (2*25.6KB). 2 nodes per block-iter,
// thread j in [0,128) computes output feature j for its node. Grid-stride.
// ---------------------------------------------------------------------------
__global__ __launch_bounds__(256) void layer1_kernel(
    const float* __restrict__ x,
    const float* __restrict__ aggx,
    const float* __restrict__ deg,
    const float* __restrict__ W1l,
    const float* __restrict__ W1r,
    const float* __restrict__ b1,
    float* __restrict__ h)
{
    __shared__ float sWl[D_IN * HIDDEN];
    __shared__ float sWr[D_IN * HIDDEN];
    __shared__ float sb[HIDDEN];
    __shared__ float sx[2][D_IN];
    __shared__ float sa[2][D_IN];

    for (int i = threadIdx.x; i < D_IN * HIDDEN; i += 256) {
        sWl[i] = W1l[i];
        sWr[i] = W1r[i];
    }
    if (threadIdx.x < HIDDEN) sb[threadIdx.x] = b1[threadIdx.x];

    const int j    = threadIdx.x & 127;
    const int half = threadIdx.x >> 7;   // 0 or 1: which node of the pair

    for (int base = blockIdx.x * 2; base < N_NODES; base += gridDim.x * 2) {
        int n = base + half;
        __syncthreads();   // covers W-load (iter 0) and prior-iter LDS reuse
        if (n < N_NODES && j < D_IN) {
            sx[half][j] = x[n * D_IN + j];
            sa[half][j] = aggx[n * D_IN + j];
        }
        __syncthreads();
        if (n < N_NODES) {
            float inv  = 1.0f / fmaxf(deg[n], 1.0f);
            float accA = 0.0f, accX = 0.0f;
            #pragma unroll
            for (int d = 0; d < D_IN; ++d) {
                accA += sa[half][d] * sWl[d * HIDDEN + j];
                accX += sx[half][d] * sWr[d * HIDDEN + j];
            }
            h[n * HIDDEN + j] = fmaxf(accA * inv + accX + sb[j], 0.0f);
        }
    }
}

// ---------------------------------------------------------------------------
// Kernel 3: p = h @ W2_l ; q = h @ W2_r + b2   (both [N, 8])
// 8 threads per node (one per class); h row read as float4 (broadcast within
// the 8-lane group). W2 in LDS (2*4KB).
// ---------------------------------------------------------------------------
__global__ __launch_bounds__(256) void pq_kernel(
    const float* __restrict__ h,
    const float* __restrict__ W2l,
    const float* __restrict__ W2r,
    const float* __restrict__ b2,
    float* __restrict__ p,
    float* __restrict__ q)
{
    __shared__ float sl[HIDDEN * NCLS];
    __shared__ float sr[HIDDEN * NCLS];
    __shared__ float sb[NCLS];
    for (int i = threadIdx.x; i < HIDDEN * NCLS; i += 256) {
        sl[i] = W2l[i];
        sr[i] = W2r[i];
    }
    if (threadIdx.x < NCLS) sb[threadIdx.x] = b2[threadIdx.x];
    __syncthreads();

    int tid = blockIdx.x * 256 + threadIdx.x;
    int n = tid >> 3;
    int c = tid & 7;
    if (n >= N_NODES) return;

    const float4* h4 = reinterpret_cast<const float4*>(h + n * HIDDEN);
    float accl = 0.0f, accr = 0.0f;
    #pragma unroll
    for (int d4 = 0; d4 < HIDDEN / 4; ++d4) {
        float4 v = h4[d4];
        int d = d4 * 4;
        accl += v.x * sl[(d + 0) * NCLS + c] + v.y * sl[(d + 1) * NCLS + c]
              + v.z * sl[(d + 2) * NCLS + c] + v.w * sl[(d + 3) * NCLS + c];
        accr += v.x * sr[(d + 0) * NCLS + c] + v.y * sr[(d + 1) * NCLS + c]
              + v.z * sr[(d + 2) * NCLS + c] + v.w * sr[(d + 3) * NCLS + c];
    }
    p[tid] = accl;
    q[tid] = accr + sb[c];
}

// ---------------------------------------------------------------------------
// Kernel 4: scatter p rows: aggp[dst] += p[src]  (8 floats/edge)
// ---------------------------------------------------------------------------
__global__ __launch_bounds__(256) void scatter_p(
    const float* __restrict__ p,
    const int*   __restrict__ src,
    const int*   __restrict__ dst,
    float* __restrict__ aggp)
{
    int tid = blockIdx.x * 256 + threadIdx.x;
    int e = tid >> 3;
    int c = tid & 7;
    if (e >= N_EDGES) return;
    atomicAdd(&aggp[dst[e] * NCLS + c], p[src[e] * NCLS + c]);
}

// ---------------------------------------------------------------------------
// Kernel 5: out = aggp / max(deg,1) + q
// ---------------------------------------------------------------------------
__global__ __launch_bounds__(256) void final_kernel(
    const float* __restrict__ aggp,
    const float* __restrict__ q,
    const float* __restrict__ deg,
    float* __restrict__ out)
{
    int tid = blockIdx.x * 256 + threadIdx.x;
    if (tid >= N_NODES * NCLS) return;
    int n = tid >> 3;
    out[tid] = aggp[tid] / fmaxf(deg[n], 1.0f) + q[tid];
}

extern "C" void kernel_launch(void* const* d_in, const int* in_sizes, int n_in,
                              void* d_out, int out_size, void* d_ws, size_t ws_size,
                              hipStream_t stream)
{
    const float* x   = (const float*)d_in[0];
    const int*   ei  = (const int*)  d_in[1];   // [2, E] — src row then dst row
    const float* W1l = (const float*)d_in[2];
    const float* W1r = (const float*)d_in[3];
    const float* b1  = (const float*)d_in[4];
    const float* W2l = (const float*)d_in[5];
    const float* W2r = (const float*)d_in[6];
    const float* b2  = (const float*)d_in[7];
    float* out = (float*)d_out;

    const int* src = ei;
    const int* dst = ei + N_EDGES;

    // Workspace layout (floats)
    float* ws   = (float*)d_ws;
    float* deg  = ws;                                  // N
    float* aggx = deg  + N_NODES;                      // N * 50
    float* h    = aggx + (size_t)N_NODES * D_IN;       // N * 128
    float* p    = h    + (size_t)N_NODES * HIDDEN;     // N * 8
    float* q    = p    + (size_t)N_NODES * NCLS;       // N * 8
    float* aggp = q    + (size_t)N_NODES * NCLS;       // N * 8

    // Zero the accumulated buffers (poisoned 0xAA otherwise; not re-poisoned
    // between replays, so we must clear every call).
    hipMemsetAsync(deg,  0, sizeof(float) * N_NODES, stream);
    hipMemsetAsync(aggx, 0, sizeof(float) * (size_t)N_NODES * D_IN, stream);
    hipMemsetAsync(aggp, 0, sizeof(float) * (size_t)N_NODES * NCLS, stream);

    // 1) aggregate x over edges + degree
    {
        int blocks = (N_EDGES * 64) / 256;   // exact: 400000
        scatter_x_deg<<<blocks, 256, 0, stream>>>(x, src, dst, aggx, deg);
    }
    // 2) h = relu(aggx/deg @ W1l + x @ W1r + b1)
    layer1_kernel<<<1024, 256, 0, stream>>>(x, aggx, deg, W1l, W1r, b1, h);

    // 3) p = h@W2l, q = h@W2r + b2
    {
        int blocks = (N_NODES * NCLS + 255) / 256;  // 3125
        pq_kernel<<<blocks, 256, 0, stream>>>(h, W2l, W2r, b2, p, q);
    }
    // 4) aggp[dst] += p[src]
    {
        int blocks = (N_EDGES * NCLS) / 256;  // 50000
        scatter_p<<<blocks, 256, 0, stream>>>(p, src, dst, aggp);
    }
    // 5) out = aggp/deg + q
    {
        int blocks = (N_NODES * NCLS + 255) / 256;
        final_kernel<<<blocks, 256, 0, stream>>>(aggp, q, deg, out);
    }
}

// Round 2
// 512.840 us; speedup vs baseline: 1.4195x; 1.4195x over previous
//
#include <hip/hip_runtime.h>

// Problem constants (from reference)
#define N_NODES 100000
#define N_EDGES 1600000
#define D_IN    50
#define HIDDEN  128
#define NCLS    8

// ===========================================================================
// CSR construction: counting-sort edges by dst each call (deterministic work).
// ===========================================================================

// deg_int[t]++ for each edge
__global__ __launch_bounds__(256) void hist_kernel(
    const int* __restrict__ dst, int* __restrict__ deg_int)
{
    int e = blockIdx.x * 256 + threadIdx.x;
    if (e < N_EDGES) atomicAdd(&deg_int[dst[e]], 1);
}

// per-block exclusive scan of deg_int -> offs, block totals -> bsum
__global__ __launch_bounds__(256) void scan1_kernel(
    const int* __restrict__ deg_int, int* __restrict__ offs, int* __restrict__ bsum)
{
    __shared__ int s[256];
    int tid = threadIdx.x;
    int i = blockIdx.x * 256 + tid;
    int v = (i < N_NODES) ? deg_int[i] : 0;
    s[tid] = v;
    __syncthreads();
    for (int d = 1; d < 256; d <<= 1) {
        int t = (tid >= d) ? s[tid - d] : 0;
        __syncthreads();
        s[tid] += t;
        __syncthreads();
    }
    if (i < N_NODES) offs[i] = s[tid] - v;          // exclusive
    if (tid == 255) bsum[blockIdx.x] = s[255];      // block total
}

// single-block exclusive scan of the 391 block totals (padded to 512)
__global__ __launch_bounds__(512) void scan2_kernel(int* __restrict__ bsum, int nb)
{
    __shared__ int s[512];
    int tid = threadIdx.x;
    int v = (tid < nb) ? bsum[tid] : 0;
    s[tid] = v;
    __syncthreads();
    for (int d = 1; d < 512; d <<= 1) {
        int t = (tid >= d) ? s[tid - d] : 0;
        __syncthreads();
        s[tid] += t;
        __syncthreads();
    }
    if (tid < nb) bsum[tid] = s[tid] - v;           // exclusive
}

// add block offsets; write sentinel offs[N] = E
__global__ __launch_bounds__(256) void scan3_kernel(
    int* __restrict__ offs, const int* __restrict__ bsum)
{
    int i = blockIdx.x * 256 + threadIdx.x;
    if (i < N_NODES) offs[i] += bsum[i >> 8];
    if (i == 0) offs[N_NODES] = N_EDGES;
}

// bucket-fill: sorted_src groups all edges of a dst contiguously
__global__ __launch_bounds__(256) void build_kernel(
    const int* __restrict__ src, const int* __restrict__ dst,
    int* __restrict__ cursor, int* __restrict__ sorted_src)
{
    int e = blockIdx.x * 256 + threadIdx.x;
    if (e >= N_EDGES) return;
    int t = dst[e];
    int pos = atomicAdd(&cursor[t], 1);
    sorted_src[pos] = src[e];
}

// ===========================================================================
// Gather-aggregate x (mean folded in): one 64-lane wave per node.
// ===========================================================================
__global__ __launch_bounds__(256) void agg_x_kernel(
    const float* __restrict__ x,
    const int*   __restrict__ offs,
    const int*   __restrict__ sorted_src,
    float* __restrict__ aggm)
{
    int node = blockIdx.x * 4 + (threadIdx.x >> 6);
    int d = threadIdx.x & 63;
    if (node >= N_NODES) return;
    int beg = offs[node], end = offs[node + 1];
    float acc = 0.0f;
    for (int i = beg; i < end; ++i) {
        int s = sorted_src[i];                 // wave-uniform load
        if (d < D_IN) acc += x[s * D_IN + d];  // 200B contiguous row
    }
    float inv = 1.0f / fmaxf((float)(end - beg), 1.0f);
    if (d < D_IN) aggm[node * D_IN + d] = acc * inv;
}

// ===========================================================================
// Layer 1: h = relu(aggm @ W1l + x @ W1r + b1)
// Weight columns in VGPRs (100 regs); node input rows broadcast from LDS via
// float4 reads. 2 nodes per block-iter, thread j in [0,128) = output feature.
// ===========================================================================
__global__ __launch_bounds__(256) void layer1_kernel(
    const float* __restrict__ x,
    const float* __restrict__ aggm,
    const float* __restrict__ W1l,
    const float* __restrict__ W1r,
    const float* __restrict__ b1,
    float* __restrict__ h)
{
    __shared__ alignas(16) float sx[2][56];
    __shared__ alignas(16) float sa[2][56];

    const int j    = threadIdx.x & 127;
    const int half = threadIdx.x >> 7;

    float wl[D_IN], wr[D_IN];
    #pragma unroll
    for (int d = 0; d < D_IN; ++d) {
        wl[d] = W1l[d * HIDDEN + j];
        wr[d] = W1r[d * HIDDEN + j];
    }
    const float bj = b1[j];

    for (int base = blockIdx.x * 2; base < N_NODES; base += gridDim.x * 2) {
        int n = base + half;
        __syncthreads();   // protect prior-iter LDS reads
        if (n < N_NODES && j < D_IN) {
            sx[half][j] = x[n * D_IN + j];
            sa[half][j] = aggm[n * D_IN + j];
        }
        __syncthreads();
        if (n < N_NODES) {
            const float4* sx4 = reinterpret_cast<const float4*>(&sx[half][0]);
            const float4* sa4 = reinterpret_cast<const float4*>(&sa[half][0]);
            float accA = 0.0f, accX = 0.0f;
            #pragma unroll
            for (int k = 0; k < 12; ++k) {
                float4 vx = sx4[k];
                float4 va = sa4[k];
                int d = 4 * k;
                accX += vx.x * wr[d] + vx.y * wr[d + 1] + vx.z * wr[d + 2] + vx.w * wr[d + 3];
                accA += va.x * wl[d] + va.y * wl[d + 1] + va.z * wl[d + 2] + va.w * wl[d + 3];
            }
            accX += sx[half][48] * wr[48] + sx[half][49] * wr[49];
            accA += sa[half][48] * wl[48] + sa[half][49] * wl[49];
            h[n * HIDDEN + j] = fmaxf(accA + accX + bj, 0.0f);
        }
    }
}

// ===========================================================================
// p = h @ W2_l ; q = h @ W2_r + b2
// ===========================================================================
__global__ __launch_bounds__(256) void pq_kernel(
    const float* __restrict__ h,
    const float* __restrict__ W2l,
    const float* __restrict__ W2r,
    const float* __restrict__ b2,
    float* __restrict__ p,
    float* __restrict__ q)
{
    __shared__ float sl[HIDDEN * NCLS];
    __shared__ float sr[HIDDEN * NCLS];
    __shared__ float sb[NCLS];
    for (int i = threadIdx.x; i < HIDDEN * NCLS; i += 256) {
        sl[i] = W2l[i];
        sr[i] = W2r[i];
    }
    if (threadIdx.x < NCLS) sb[threadIdx.x] = b2[threadIdx.x];
    __syncthreads();

    int tid = blockIdx.x * 256 + threadIdx.x;
    int n = tid >> 3;
    int c = tid & 7;
    if (n >= N_NODES) return;

    const float4* h4 = reinterpret_cast<const float4*>(h + n * HIDDEN);
    float accl = 0.0f, accr = 0.0f;
    #pragma unroll
    for (int d4 = 0; d4 < HIDDEN / 4; ++d4) {
        float4 v = h4[d4];
        int d = d4 * 4;
        accl += v.x * sl[(d + 0) * NCLS + c] + v.y * sl[(d + 1) * NCLS + c]
              + v.z * sl[(d + 2) * NCLS + c] + v.w * sl[(d + 3) * NCLS + c];
        accr += v.x * sr[(d + 0) * NCLS + c] + v.y * sr[(d + 1) * NCLS + c]
              + v.z * sr[(d + 2) * NCLS + c] + v.w * sr[(d + 3) * NCLS + c];
    }
    p[tid] = accl;
    q[tid] = accr + sb[c];
}

// ===========================================================================
// Gather-aggregate p + final: one wave per node; lane = k*8 + c.
// out = (sum_e p[src_e]) / max(deg,1) + q
// ===========================================================================
__global__ __launch_bounds__(256) void aggp_final_kernel(
    const float* __restrict__ p,
    const float* __restrict__ q,
    const int*   __restrict__ offs,
    const int*   __restrict__ sorted_src,
    float* __restrict__ out)
{
    int node = blockIdx.x * 4 + (threadIdx.x >> 6);
    int lane = threadIdx.x & 63;
    int k = lane >> 3;
    int c = lane & 7;
    if (node >= N_NODES) return;
    int beg = offs[node], end = offs[node + 1];
    float acc = 0.0f;
    for (int i = beg + k; i < end; i += 8) {
        acc += p[sorted_src[i] * NCLS + c];
    }
    // reduce across the 8 edge-slots (lanes differing in bits 3..5)
    acc += __shfl_xor(acc, 8);
    acc += __shfl_xor(acc, 16);
    acc += __shfl_xor(acc, 32);
    if (lane < 8) {
        float inv = 1.0f / fmaxf((float)(end - beg), 1.0f);
        out[node * NCLS + c] = acc * inv + q[node * NCLS + c];
    }
}

// ===========================================================================
extern "C" void kernel_launch(void* const* d_in, const int* in_sizes, int n_in,
                              void* d_out, int out_size, void* d_ws, size_t ws_size,
                              hipStream_t stream)
{
    const float* x   = (const float*)d_in[0];
    const int*   ei  = (const int*)  d_in[1];   // [2, E] — src row then dst row
    const float* W1l = (const float*)d_in[2];
    const float* W1r = (const float*)d_in[3];
    const float* b1  = (const float*)d_in[4];
    const float* W2l = (const float*)d_in[5];
    const float* W2r = (const float*)d_in[6];
    const float* b2  = (const float*)d_in[7];
    float* out = (float*)d_out;

    const int* src = ei;
    const int* dst = ei + N_EDGES;

    // Workspace layout (4B elements)
    char* ws = (char*)d_ws;
    int*   deg_int    = (int*)ws;                                  // N
    int*   offs       = deg_int + N_NODES;                         // N+1
    int*   bsum       = offs + (N_NODES + 1);                      // 512
    int*   cursor     = bsum + 512;                                // N
    int*   sorted_src = cursor + N_NODES;                          // E
    float* aggm       = (float*)(sorted_src + N_EDGES);            // N*50
    float* h          = aggm + (size_t)N_NODES * D_IN;             // N*128
    // p/q reuse the aggm region (dead after layer1): N*8 each <= N*50
    float* p          = aggm;
    float* q          = aggm + (size_t)N_NODES * NCLS;

    hipMemsetAsync(deg_int, 0, sizeof(int) * N_NODES, stream);

    // --- CSR build ---
    hist_kernel <<<(N_EDGES + 255) / 256, 256, 0, stream>>>(dst, deg_int);
    const int nb = (N_NODES + 255) / 256;   // 391
    scan1_kernel<<<nb, 256, 0, stream>>>(deg_int, offs, bsum);
    scan2_kernel<<<1, 512, 0, stream>>>(bsum, nb);
    scan3_kernel<<<nb + 1, 256, 0, stream>>>(offs, bsum);
    hipMemcpyAsync(cursor, offs, sizeof(int) * N_NODES, hipMemcpyDeviceToDevice, stream);
    build_kernel<<<(N_EDGES + 255) / 256, 256, 0, stream>>>(src, dst, cursor, sorted_src);

    // --- Layer 1 ---
    agg_x_kernel<<<(N_NODES + 3) / 4, 256, 0, stream>>>(x, offs, sorted_src, aggm);
    layer1_kernel<<<1024, 256, 0, stream>>>(x, aggm, W1l, W1r, b1, h);

    // --- Layer 2 ---
    pq_kernel<<<(N_NODES * NCLS + 255) / 256, 256, 0, stream>>>(h, W2l, W2r, b2, p, q);
    aggp_final_kernel<<<(N_NODES + 3) / 4, 256, 0, stream>>>(p, q, offs, sorted_src, out);
}

// Round 4
// 429.825 us; speedup vs baseline: 1.6936x; 1.1931x over previous
//
#include <hip/hip_runtime.h>

// Problem constants (from reference)
#define N_NODES 100000
#define N_EDGES 1600000
#define D_IN    50
#define HIDDEN  128
#define NCLS    8

// ---------------------------------------------------------------------------
// Helpers: bf16 pack/unpack (RNE)
// ---------------------------------------------------------------------------
__device__ __forceinline__ unsigned short f2bf(float f) {
    union { float f; unsigned u; } a; a.f = f;
    unsigned u = a.u;
    return (unsigned short)((u + 0x7FFFu + ((u >> 16) & 1u)) >> 16);
}
__device__ __forceinline__ float bf_lo(unsigned v) { return __uint_as_float(v << 16); }
__device__ __forceinline__ float bf_hi(unsigned v) { return __uint_as_float(v & 0xFFFF0000u); }

// ===========================================================================
// x -> packed bf16 rows: xb[n][25] (each uint = 2 bf16)
// ===========================================================================
__global__ __launch_bounds__(256) void conv_x_kernel(
    const float* __restrict__ x, unsigned* __restrict__ xb)
{
    int t = blockIdx.x * 256 + threadIdx.x;
    if (t >= N_NODES * 25) return;
    float2 v = ((const float2*)x)[t];
    xb[t] = (unsigned)f2bf(v.x) | ((unsigned)f2bf(v.y) << 16);
}

// ===========================================================================
// CSR construction (counting sort by dst)
// ===========================================================================
__global__ __launch_bounds__(256) void hist_kernel(
    const int* __restrict__ dst, int* __restrict__ deg_int)
{
    int e = blockIdx.x * 256 + threadIdx.x;
    if (e < N_EDGES) atomicAdd(&deg_int[dst[e]], 1);
}

__global__ __launch_bounds__(256) void scan1_kernel(
    const int* __restrict__ deg_int, int* __restrict__ offs, int* __restrict__ bsum)
{
    __shared__ int s[256];
    int tid = threadIdx.x;
    int i = blockIdx.x * 256 + tid;
    int v = (i < N_NODES) ? deg_int[i] : 0;
    s[tid] = v;
    __syncthreads();
    for (int d = 1; d < 256; d <<= 1) {
        int t = (tid >= d) ? s[tid - d] : 0;
        __syncthreads();
        s[tid] += t;
        __syncthreads();
    }
    if (i < N_NODES) offs[i] = s[tid] - v;          // exclusive
    if (tid == 255) bsum[blockIdx.x] = s[255];      // block total
}

__global__ __launch_bounds__(512) void scan2_kernel(int* __restrict__ bsum, int nb)
{
    __shared__ int s[512];
    int tid = threadIdx.x;
    int v = (tid < nb) ? bsum[tid] : 0;
    s[tid] = v;
    __syncthreads();
    for (int d = 1; d < 512; d <<= 1) {
        int t = (tid >= d) ? s[tid - d] : 0;
        __syncthreads();
        s[tid] += t;
        __syncthreads();
    }
    if (tid < nb) bsum[tid] = s[tid] - v;           // exclusive
}

__global__ __launch_bounds__(256) void scan3_kernel(
    int* __restrict__ offs, const int* __restrict__ bsum, int* __restrict__ cursor)
{
    int i = blockIdx.x * 256 + threadIdx.x;
    if (i < N_NODES) {
        int v = offs[i] + bsum[i >> 8];
        offs[i]   = v;
        cursor[i] = v;
    }
    if (i == 0) offs[N_NODES] = N_EDGES;
}

__global__ __launch_bounds__(256) void build_kernel(
    const int* __restrict__ src, const int* __restrict__ dst,
    int* __restrict__ cursor, int* __restrict__ sorted_src)
{
    int e = blockIdx.x * 256 + threadIdx.x;
    if (e >= N_EDGES) return;
    int t = dst[e];
    int pos = atomicAdd(&cursor[t], 1);
    sorted_src[pos] = src[e];
}

// ===========================================================================
// Gather-aggregate bf16 x rows (mean folded in). One wave per node, 2 edges
// in flight (half-wave split), index prefetch to break the load->load chain.
// Row = 50 bf16 = 25 dwords; lane (par=lane>>5, dw=lane&31), dw<25 active.
// ===========================================================================
__global__ __launch_bounds__(256) void agg_x_kernel(
    const unsigned* __restrict__ xb,
    const int*      __restrict__ offs,
    const int*      __restrict__ ss,
    float* __restrict__ aggm)
{
    int node = blockIdx.x * 4 + (threadIdx.x >> 6);
    int lane = threadIdx.x & 63;
    int par = lane >> 5;
    int dw  = lane & 31;
    if (node >= N_NODES) return;
    int beg = offs[node], end = offs[node + 1];
    float2 acc = make_float2(0.0f, 0.0f);
    int i = beg + par;
    int sNext = (i < end) ? ss[i] : 0;
    for (; i < end; i += 2) {
        int s = sNext;
        int i2 = i + 2;
        sNext = (i2 < end) ? ss[i2] : 0;
        if (dw < 25) {
            unsigned v = xb[s * 25 + dw];
            acc.x += bf_lo(v);
            acc.y += bf_hi(v);
        }
    }
    acc.x += __shfl_xor(acc.x, 32);
    acc.y += __shfl_xor(acc.y, 32);
    if (par == 0 && dw < 25) {
        float inv = 1.0f / fmaxf((float)(end - beg), 1.0f);
        ((float2*)(aggm + (size_t)node * D_IN))[dw] =
            make_float2(acc.x * inv, acc.y * inv);
    }
}

// ===========================================================================
// Layer 1: h = relu(aggm @ W1l + x @ W1r + b1)
// Weight columns in VGPRs (100 regs); node rows broadcast from LDS as float4.
// ===========================================================================
__global__ __launch_bounds__(256) void layer1_kernel(
    const float* __restrict__ x,
    const float* __restrict__ aggm,
    const float* __restrict__ W1l,
    const float* __restrict__ W1r,
    const float* __restrict__ b1,
    float* __restrict__ h)
{
    __shared__ alignas(16) float sx[2][56];
    __shared__ alignas(16) float sa[2][56];

    const int j    = threadIdx.x & 127;
    const int half = threadIdx.x >> 7;

    float wl[D_IN], wr[D_IN];
    #pragma unroll
    for (int d = 0; d < D_IN; ++d) {
        wl[d] = W1l[d * HIDDEN + j];
        wr[d] = W1r[d * HIDDEN + j];
    }
    const float bj = b1[j];

    for (int base = blockIdx.x * 2; base < N_NODES; base += gridDim.x * 2) {
        int n = base + half;
        __syncthreads();
        if (n < N_NODES && j < D_IN) {
            sx[half][j] = x[n * D_IN + j];
            sa[half][j] = aggm[n * D_IN + j];
        }
        __syncthreads();
        if (n < N_NODES) {
            const float4* sx4 = reinterpret_cast<const float4*>(&sx[half][0]);
            const float4* sa4 = reinterpret_cast<const float4*>(&sa[half][0]);
            float accA = 0.0f, accX = 0.0f;
            #pragma unroll
            for (int k = 0; k < 12; ++k) {
                float4 vx = sx4[k];
                float4 va = sa4[k];
                int d = 4 * k;
                accX += vx.x * wr[d] + vx.y * wr[d + 1] + vx.z * wr[d + 2] + vx.w * wr[d + 3];
                accA += va.x * wl[d] + va.y * wl[d + 1] + va.z * wl[d + 2] + va.w * wl[d + 3];
            }
            accX += sx[half][48] * wr[48] + sx[half][49] * wr[49];
            accA += sa[half][48] * wl[48] + sa[half][49] * wl[49];
            h[(size_t)n * HIDDEN + j] = fmaxf(accA + accX + bj, 0.0f);
        }
    }
}

// ===========================================================================
// p (bf16) = h @ W2_l ; q (f32) = h @ W2_r + b2
// ===========================================================================
__global__ __launch_bounds__(256) void pq_kernel(
    const float* __restrict__ h,
    const float* __restrict__ W2l,
    const float* __restrict__ W2r,
    const float* __restrict__ b2,
    unsigned short* __restrict__ pb,
    float* __restrict__ q)
{
    __shared__ float sl[HIDDEN * NCLS];
    __shared__ float sr[HIDDEN * NCLS];
    __shared__ float sb[NCLS];
    for (int i = threadIdx.x; i < HIDDEN * NCLS; i += 256) {
        sl[i] = W2l[i];
        sr[i] = W2r[i];
    }
    if (threadIdx.x < NCLS) sb[threadIdx.x] = b2[threadIdx.x];
    __syncthreads();

    int tid = blockIdx.x * 256 + threadIdx.x;
    int n = tid >> 3;
    int c = tid & 7;
    if (n >= N_NODES) return;

    const float4* h4 = reinterpret_cast<const float4*>(h + (size_t)n * HIDDEN);
    float accl = 0.0f, accr = 0.0f;
    #pragma unroll
    for (int d4 = 0; d4 < HIDDEN / 4; ++d4) {
        float4 v = h4[d4];
        int d = d4 * 4;
        accl += v.x * sl[(d + 0) * NCLS + c] + v.y * sl[(d + 1) * NCLS + c]
              + v.z * sl[(d + 2) * NCLS + c] + v.w * sl[(d + 3) * NCLS + c];
        accr += v.x * sr[(d + 0) * NCLS + c] + v.y * sr[(d + 1) * NCLS + c]
              + v.z * sr[(d + 2) * NCLS + c] + v.w * sr[(d + 3) * NCLS + c];
    }
    pb[tid] = f2bf(accl);
    q[tid]  = accr + sb[c];
}

// ===========================================================================
// Gather-aggregate bf16 p rows + final. One wave per node, 16 edges in
// flight; lane = (k=lane>>2)*4 + c2, c2 covers classes {2c2, 2c2+1}.
// out = (sum p[src]) / max(deg,1) + q
// ===========================================================================
__global__ __launch_bounds__(256) void aggp_final_kernel(
    const unsigned* __restrict__ pb,   // [N][4] dwords (8 bf16)
    const float*    __restrict__ q,
    const int*      __restrict__ offs,
    const int*      __restrict__ ss,
    float* __restrict__ out)
{
    int node = blockIdx.x * 4 + (threadIdx.x >> 6);
    int lane = threadIdx.x & 63;
    int k  = lane >> 2;
    int c2 = lane & 3;
    if (node >= N_NODES) return;
    int beg = offs[node], end = offs[node + 1];
    float2 acc = make_float2(0.0f, 0.0f);
    int i = beg + k;
    int sNext = (i < end) ? ss[i] : 0;
    for (; i < end; i += 16) {
        int s = sNext;
        int i2 = i + 16;
        sNext = (i2 < end) ? ss[i2] : 0;
        unsigned v = pb[s * 4 + c2];
        acc.x += bf_lo(v);
        acc.y += bf_hi(v);
    }
    acc.x += __shfl_xor(acc.x, 4);  acc.y += __shfl_xor(acc.y, 4);
    acc.x += __shfl_xor(acc.x, 8);  acc.y += __shfl_xor(acc.y, 8);
    acc.x += __shfl_xor(acc.x, 16); acc.y += __shfl_xor(acc.y, 16);
    acc.x += __shfl_xor(acc.x, 32); acc.y += __shfl_xor(acc.y, 32);
    if (lane < 4) {
        float inv = 1.0f / fmaxf((float)(end - beg), 1.0f);
        float2 qq = ((const float2*)(q + (size_t)node * NCLS))[c2];
        ((float2*)(out + (size_t)node * NCLS))[c2] =
            make_float2(acc.x * inv + qq.x, acc.y * inv + qq.y);
    }
}

// ===========================================================================
extern "C" void kernel_launch(void* const* d_in, const int* in_sizes, int n_in,
                              void* d_out, int out_size, void* d_ws, size_t ws_size,
                              hipStream_t stream)
{
    const float* x   = (const float*)d_in[0];
    const int*   ei  = (const int*)  d_in[1];
    const float* W1l = (const float*)d_in[2];
    const float* W1r = (const float*)d_in[3];
    const float* b1  = (const float*)d_in[4];
    const float* W2l = (const float*)d_in[5];
    const float* W2r = (const float*)d_in[6];
    const float* b2  = (const float*)d_in[7];
    float* out = (float*)d_out;

    const int* src = ei;
    const int* dst = ei + N_EDGES;

    // Workspace layout (dword units; sizes padded so aggm/h are 16B aligned)
    int* ws = (int*)d_ws;
    int*   deg_int    = ws;                               // N        (100000)
    int*   offs       = deg_int + N_NODES;                // N+4      (100004)
    int*   bsum       = offs + (N_NODES + 4);             // 512
    int*   cursor     = bsum + 512;                       // N
    int*   sorted_src = cursor + N_NODES;                 // E
    float* aggm       = (float*)(sorted_src + N_EDGES);   // N*50
    float* h          = aggm + (size_t)N_NODES * D_IN;    // N*128
    // xb overlays h (xb dead before layer1 writes h): N*25 dwords <= N*128
    unsigned* xb      = (unsigned*)h;
    // pb/q overlay aggm (dead after layer1): N*4 + N*8 dwords <= N*50
    unsigned short* pb = (unsigned short*)aggm;           // N*8 ushorts
    float* q           = aggm + (size_t)N_NODES * 4;      // N*8 floats

    (void)hipMemsetAsync(deg_int, 0, sizeof(int) * N_NODES, stream);

    // x -> bf16 packed
    conv_x_kernel<<<(N_NODES * 25 + 255) / 256, 256, 0, stream>>>(x, xb);

    // CSR build
    hist_kernel <<<(N_EDGES + 255) / 256, 256, 0, stream>>>(dst, deg_int);
    const int nb = (N_NODES + 255) / 256;   // 391
    scan1_kernel<<<nb, 256, 0, stream>>>(deg_int, offs, bsum);
    scan2_kernel<<<1, 512, 0, stream>>>(bsum, nb);
    scan3_kernel<<<nb, 256, 0, stream>>>(offs, bsum, cursor);
    build_kernel<<<(N_EDGES + 255) / 256, 256, 0, stream>>>(src, dst, cursor, sorted_src);

    // Layer 1
    agg_x_kernel<<<(N_NODES + 3) / 4, 256, 0, stream>>>(xb, offs, sorted_src, aggm);
    layer1_kernel<<<1024, 256, 0, stream>>>(x, aggm, W1l, W1r, b1, h);

    // Layer 2
    pq_kernel<<<(N_NODES * NCLS + 255) / 256, 256, 0, stream>>>(h, W2l, W2r, b2, pb, q);
    aggp_final_kernel<<<(N_NODES + 3) / 4, 256, 0, stream>>>(
        (const unsigned*)pb, q, offs, sorted_src, out);
}

// Round 5
// 276.568 us; speedup vs baseline: 2.6321x; 1.5541x over previous
//
#include <hip/hip_runtime.h>

// Problem constants (from reference)
#define N_NODES 100000
#define N_EDGES 1600000
#define D_IN    50
#define HIDDEN  128
#define NCLS    8

// Bucket-sort parameters
#define TILE    4096
#define NTILES  ((N_EDGES + TILE - 1) / TILE)   // 391
#define BSHIFT  9
#define NB      196                              // ceil(100000 / 512)

// ---------------------------------------------------------------------------
// Helpers: bf16 pack/unpack (RNE)
// ---------------------------------------------------------------------------
__device__ __forceinline__ unsigned short f2bf(float f) {
    union { float f; unsigned u; } a; a.f = f;
    unsigned u = a.u;
    return (unsigned short)((u + 0x7FFFu + ((u >> 16) & 1u)) >> 16);
}
__device__ __forceinline__ float bf_lo(unsigned v) { return __uint_as_float(v << 16); }
__device__ __forceinline__ float bf_hi(unsigned v) { return __uint_as_float(v & 0xFFFF0000u); }

// ===========================================================================
// x -> packed bf16 rows: xb[n][25] (each uint = 2 bf16)
// ===========================================================================
__global__ __launch_bounds__(256) void conv_x_kernel(
    const float* __restrict__ x, unsigned* __restrict__ xb)
{
    int t = blockIdx.x * 256 + threadIdx.x;
    if (t >= N_NODES * 25) return;
    float2 v = ((const float2*)x)[t];
    xb[t] = (unsigned)f2bf(v.x) | ((unsigned)f2bf(v.y) << 16);
}

// ===========================================================================
// passA: per-tile bucket histogram (LDS atomics), g_hist[tile][NB]
// ===========================================================================
__global__ __launch_bounds__(256) void passA_kernel(
    const int* __restrict__ dst, int* __restrict__ g_hist)
{
    __shared__ int lh[NB];
    int tid = threadIdx.x;
    for (int i = tid; i < NB; i += 256) lh[i] = 0;
    __syncthreads();
    int base = blockIdx.x * TILE;
    int cnt = min(TILE, N_EDGES - base);
    for (int i = tid; i < cnt; i += 256)
        atomicAdd(&lh[dst[base + i] >> BSHIFT], 1);
    __syncthreads();
    for (int i = tid; i < NB; i += 256) g_hist[blockIdx.x * NB + i] = lh[i];
}

// ===========================================================================
// passB: per-bucket exclusive scan over tiles; btot[b] = bucket total
// ===========================================================================
__global__ __launch_bounds__(512) void passB_kernel(
    int* __restrict__ g_hist, int* __restrict__ btot)
{
    __shared__ int s[512];
    int b = blockIdx.x, tid = threadIdx.x;
    int v = (tid < NTILES) ? g_hist[tid * NB + b] : 0;
    s[tid] = v;
    __syncthreads();
    for (int d = 1; d < 512; d <<= 1) {
        int t = (tid >= d) ? s[tid - d] : 0;
        __syncthreads();
        s[tid] += t;
        __syncthreads();
    }
    if (tid < NTILES) g_hist[tid * NB + b] = s[tid] - v;   // exclusive over tiles
    if (tid == 511) btot[b] = s[511];
}

// ===========================================================================
// passB2: exclusive scan of btot -> bbase; sentinel offs[N] = E
// ===========================================================================
__global__ __launch_bounds__(256) void passB2_kernel(
    const int* __restrict__ btot, int* __restrict__ bbase, int* __restrict__ offs)
{
    __shared__ int s[256];
    int tid = threadIdx.x;
    int v = (tid < NB) ? btot[tid] : 0;
    s[tid] = v;
    __syncthreads();
    for (int d = 1; d < 256; d <<= 1) {
        int t = (tid >= d) ? s[tid - d] : 0;
        __syncthreads();
        s[tid] += t;
        __syncthreads();
    }
    if (tid < NB) bbase[tid] = s[tid] - v;
    if (tid == 0) offs[N_NODES] = N_EDGES;
}

// ===========================================================================
// passC: reorder tile by bucket in LDS, coalesced flush to bk_src/bk_dst
// ===========================================================================
__global__ __launch_bounds__(256) void passC_kernel(
    const int* __restrict__ src, const int* __restrict__ dst,
    const int* __restrict__ g_hist, const int* __restrict__ bbase,
    int* __restrict__ bk_src, int* __restrict__ bk_dst)
{
    __shared__ int hist[NB];
    __shared__ int seg[NB];
    __shared__ int cur[NB];
    __shared__ int gof[NB];
    __shared__ int sc[256];
    __shared__ int s_src[TILE];
    __shared__ int s_dst[TILE];
    __shared__ unsigned short s_bkt[TILE];

    int tid = threadIdx.x, tile = blockIdx.x;
    int base = tile * TILE;
    int cnt = min(TILE, N_EDGES - base);

    for (int i = tid; i < NB; i += 256) {
        hist[i] = 0;
        gof[i] = g_hist[tile * NB + i] + bbase[i];
    }
    __syncthreads();

    int es[16], ed[16];
    #pragma unroll
    for (int k = 0; k < 16; ++k) {
        int i = tid + k * 256;
        if (i < cnt) {
            es[k] = src[base + i];
            ed[k] = dst[base + i];
            atomicAdd(&hist[ed[k] >> BSHIFT], 1);
        }
    }
    __syncthreads();

    // exclusive scan of hist[NB] (padded to 256)
    {
        int v = (tid < NB) ? hist[tid] : 0;
        sc[tid] = v;
        __syncthreads();
        for (int d = 1; d < 256; d <<= 1) {
            int t = (tid >= d) ? sc[tid - d] : 0;
            __syncthreads();
            sc[tid] += t;
            __syncthreads();
        }
        if (tid < NB) { seg[tid] = sc[tid] - v; cur[tid] = sc[tid] - v; }
    }
    __syncthreads();

    #pragma unroll
    for (int k = 0; k < 16; ++k) {
        int i = tid + k * 256;
        if (i < cnt) {
            int b = ed[k] >> BSHIFT;
            int p = atomicAdd(&cur[b], 1);
            s_src[p] = es[k];
            s_dst[p] = ed[k];
            s_bkt[p] = (unsigned short)b;
        }
    }
    __syncthreads();

    for (int i = tid; i < cnt; i += 256) {
        int b = s_bkt[i];
        int g = gof[b] + (i - seg[b]);
        bk_src[g] = s_src[i];
        bk_dst[g] = s_dst[i];
    }
}

// ===========================================================================
// passD: per-bucket CSR finalize: local degree hist -> scan -> offs[] write
// -> LDS-cursor scatter of sorted_src within the bucket's L2-local window.
// ===========================================================================
__global__ __launch_bounds__(512) void passD_kernel(
    const int* __restrict__ bk_src, const int* __restrict__ bk_dst,
    const int* __restrict__ bbase, const int* __restrict__ btot,
    int* __restrict__ sorted_src, int* __restrict__ offs)
{
    __shared__ int ldeg[512];
    __shared__ int lofs[512];
    int b = blockIdx.x, tid = threadIdx.x;
    int ebase = bbase[b];
    int ecnt = btot[b];
    int nbase = b << BSHIFT;

    ldeg[tid] = 0;
    __syncthreads();
    for (int i = tid; i < ecnt; i += 512)
        atomicAdd(&ldeg[bk_dst[ebase + i] - nbase], 1);
    __syncthreads();

    int v = ldeg[tid];
    lofs[tid] = v;
    __syncthreads();
    for (int d = 1; d < 512; d <<= 1) {
        int t = (tid >= d) ? lofs[tid - d] : 0;
        __syncthreads();
        lofs[tid] += t;
        __syncthreads();
    }
    int ex = lofs[tid] - v;   // exclusive local offset

    int node = nbase + tid;
    if (node < N_NODES) offs[node] = ebase + ex;

    ldeg[tid] = ex;           // reuse as cursor
    __syncthreads();
    for (int i = tid; i < ecnt; i += 512) {
        int dl = bk_dst[ebase + i] - nbase;
        int p = atomicAdd(&ldeg[dl], 1);
        sorted_src[ebase + p] = bk_src[ebase + i];
    }
}

// ===========================================================================
// Gather-aggregate bf16 x rows (mean folded in). One wave per node, 2 edges
// in flight (half-wave split), index prefetch to break the load->load chain.
// ===========================================================================
__global__ __launch_bounds__(256) void agg_x_kernel(
    const unsigned* __restrict__ xb,
    const int*      __restrict__ offs,
    const int*      __restrict__ ss,
    float* __restrict__ aggm)
{
    int node = blockIdx.x * 4 + (threadIdx.x >> 6);
    int lane = threadIdx.x & 63;
    int par = lane >> 5;
    int dw  = lane & 31;
    if (node >= N_NODES) return;
    int beg = offs[node], end = offs[node + 1];
    float2 acc = make_float2(0.0f, 0.0f);
    int i = beg + par;
    int sNext = (i < end) ? ss[i] : 0;
    for (; i < end; i += 2) {
        int s = sNext;
        int i2 = i + 2;
        sNext = (i2 < end) ? ss[i2] : 0;
        if (dw < 25) {
            unsigned v = xb[s * 25 + dw];
            acc.x += bf_lo(v);
            acc.y += bf_hi(v);
        }
    }
    acc.x += __shfl_xor(acc.x, 32);
    acc.y += __shfl_xor(acc.y, 32);
    if (par == 0 && dw < 25) {
        float inv = 1.0f / fmaxf((float)(end - beg), 1.0f);
        ((float2*)(aggm + (size_t)node * D_IN))[dw] =
            make_float2(acc.x * inv, acc.y * inv);
    }
}

// ===========================================================================
// Layer 1: h = relu(aggm @ W1l + x @ W1r + b1)
// ===========================================================================
__global__ __launch_bounds__(256) void layer1_kernel(
    const float* __restrict__ x,
    const float* __restrict__ aggm,
    const float* __restrict__ W1l,
    const float* __restrict__ W1r,
    const float* __restrict__ b1,
    float* __restrict__ h)
{
    __shared__ alignas(16) float sx[2][56];
    __shared__ alignas(16) float sa[2][56];

    const int j    = threadIdx.x & 127;
    const int half = threadIdx.x >> 7;

    float wl[D_IN], wr[D_IN];
    #pragma unroll
    for (int d = 0; d < D_IN; ++d) {
        wl[d] = W1l[d * HIDDEN + j];
        wr[d] = W1r[d * HIDDEN + j];
    }
    const float bj = b1[j];

    for (int base = blockIdx.x * 2; base < N_NODES; base += gridDim.x * 2) {
        int n = base + half;
        __syncthreads();
        if (n < N_NODES && j < D_IN) {
            sx[half][j] = x[n * D_IN + j];
            sa[half][j] = aggm[n * D_IN + j];
        }
        __syncthreads();
        if (n < N_NODES) {
            const float4* sx4 = reinterpret_cast<const float4*>(&sx[half][0]);
            const float4* sa4 = reinterpret_cast<const float4*>(&sa[half][0]);
            float accA = 0.0f, accX = 0.0f;
            #pragma unroll
            for (int k = 0; k < 12; ++k) {
                float4 vx = sx4[k];
                float4 va = sa4[k];
                int d = 4 * k;
                accX += vx.x * wr[d] + vx.y * wr[d + 1] + vx.z * wr[d + 2] + vx.w * wr[d + 3];
                accA += va.x * wl[d] + va.y * wl[d + 1] + va.z * wl[d + 2] + va.w * wl[d + 3];
            }
            accX += sx[half][48] * wr[48] + sx[half][49] * wr[49];
            accA += sa[half][48] * wl[48] + sa[half][49] * wl[49];
            h[(size_t)n * HIDDEN + j] = fmaxf(accA + accX + bj, 0.0f);
        }
    }
}

// ===========================================================================
// p (bf16) = h @ W2_l ; q (f32) = h @ W2_r + b2
// ===========================================================================
__global__ __launch_bounds__(256) void pq_kernel(
    const float* __restrict__ h,
    const float* __restrict__ W2l,
    const float* __restrict__ W2r,
    const float* __restrict__ b2,
    unsigned short* __restrict__ pb,
    float* __restrict__ q)
{
    __shared__ float sl[HIDDEN * NCLS];
    __shared__ float sr[HIDDEN * NCLS];
    __shared__ float sb[NCLS];
    for (int i = threadIdx.x; i < HIDDEN * NCLS; i += 256) {
        sl[i] = W2l[i];
        sr[i] = W2r[i];
    }
    if (threadIdx.x < NCLS) sb[threadIdx.x] = b2[threadIdx.x];
    __syncthreads();

    int tid = blockIdx.x * 256 + threadIdx.x;
    int n = tid >> 3;
    int c = tid & 7;
    if (n >= N_NODES) return;

    const float4* h4 = reinterpret_cast<const float4*>(h + (size_t)n * HIDDEN);
    float accl = 0.0f, accr = 0.0f;
    #pragma unroll
    for (int d4 = 0; d4 < HIDDEN / 4; ++d4) {
        float4 v = h4[d4];
        int d = d4 * 4;
        accl += v.x * sl[(d + 0) * NCLS + c] + v.y * sl[(d + 1) * NCLS + c]
              + v.z * sl[(d + 2) * NCLS + c] + v.w * sl[(d + 3) * NCLS + c];
        accr += v.x * sr[(d + 0) * NCLS + c] + v.y * sr[(d + 1) * NCLS + c]
              + v.z * sr[(d + 2) * NCLS + c] + v.w * sr[(d + 3) * NCLS + c];
    }
    pb[tid] = f2bf(accl);
    q[tid]  = accr + sb[c];
}

// ===========================================================================
// Gather-aggregate bf16 p rows + final: out = (sum p[src]) / max(deg,1) + q
// ===========================================================================
__global__ __launch_bounds__(256) void aggp_final_kernel(
    const unsigned* __restrict__ pb,   // [N][4] dwords (8 bf16)
    const float*    __restrict__ q,
    const int*      __restrict__ offs,
    const int*      __restrict__ ss,
    float* __restrict__ out)
{
    int node = blockIdx.x * 4 + (threadIdx.x >> 6);
    int lane = threadIdx.x & 63;
    int k  = lane >> 2;
    int c2 = lane & 3;
    if (node >= N_NODES) return;
    int beg = offs[node], end = offs[node + 1];
    float2 acc = make_float2(0.0f, 0.0f);
    int i = beg + k;
    int sNext = (i < end) ? ss[i] : 0;
    for (; i < end; i += 16) {
        int s = sNext;
        int i2 = i + 16;
        sNext = (i2 < end) ? ss[i2] : 0;
        unsigned v = pb[s * 4 + c2];
        acc.x += bf_lo(v);
        acc.y += bf_hi(v);
    }
    acc.x += __shfl_xor(acc.x, 4);  acc.y += __shfl_xor(acc.y, 4);
    acc.x += __shfl_xor(acc.x, 8);  acc.y += __shfl_xor(acc.y, 8);
    acc.x += __shfl_xor(acc.x, 16); acc.y += __shfl_xor(acc.y, 16);
    acc.x += __shfl_xor(acc.x, 32); acc.y += __shfl_xor(acc.y, 32);
    if (lane < 4) {
        float inv = 1.0f / fmaxf((float)(end - beg), 1.0f);
        float2 qq = ((const float2*)(q + (size_t)node * NCLS))[c2];
        ((float2*)(out + (size_t)node * NCLS))[c2] =
            make_float2(acc.x * inv + qq.x, acc.y * inv + qq.y);
    }
}

// ===========================================================================
extern "C" void kernel_launch(void* const* d_in, const int* in_sizes, int n_in,
                              void* d_out, int out_size, void* d_ws, size_t ws_size,
                              hipStream_t stream)
{
    const float* x   = (const float*)d_in[0];
    const int*   ei  = (const int*)  d_in[1];
    const float* W1l = (const float*)d_in[2];
    const float* W1r = (const float*)d_in[3];
    const float* b1  = (const float*)d_in[4];
    const float* W2l = (const float*)d_in[5];
    const float* W2r = (const float*)d_in[6];
    const float* b2  = (const float*)d_in[7];
    float* out = (float*)d_out;

    const int* src = ei;
    const int* dst = ei + N_EDGES;

    // Workspace layout (dword units)
    int* ws = (int*)d_ws;
    int*   offs       = ws;                               // N+4
    int*   g_hist     = offs + (N_NODES + 4);             // NTILES*NB = 76636
    int*   btot       = g_hist + NTILES * NB;             // 256
    int*   bbase      = btot + 256;                       // 256
    int*   sorted_src = bbase + 256;                      // E
    int*   bigreg     = sorted_src + N_EDGES;             // max(2E, N*50)
    int*   bk_src     = bigreg;                           // E
    int*   bk_dst     = bigreg + N_EDGES;                 // E
    float* aggm       = (float*)bigreg;                   // N*50 (overlays bk_*)
    float* h          = (float*)(bigreg + (size_t)N_NODES * D_IN);  // N*128
    unsigned* xb      = (unsigned*)h;                     // N*25 (dead before h write)
    unsigned short* pb = (unsigned short*)aggm;           // N*8 ushorts (after layer1)
    float* q           = aggm + (size_t)N_NODES * 4;      // N*8 floats

    // x -> bf16 packed
    conv_x_kernel<<<(N_NODES * 25 + 255) / 256, 256, 0, stream>>>(x, xb);

    // CSR build via two-level bucket sort
    passA_kernel <<<NTILES, 256, 0, stream>>>(dst, g_hist);
    passB_kernel <<<NB, 512, 0, stream>>>(g_hist, btot);
    passB2_kernel<<<1, 256, 0, stream>>>(btot, bbase, offs);
    passC_kernel <<<NTILES, 256, 0, stream>>>(src, dst, g_hist, bbase, bk_src, bk_dst);
    passD_kernel <<<NB, 512, 0, stream>>>(bk_src, bk_dst, bbase, btot, sorted_src, offs);

    // Layer 1
    agg_x_kernel<<<(N_NODES + 3) / 4, 256, 0, stream>>>(xb, offs, sorted_src, aggm);
    layer1_kernel<<<1024, 256, 0, stream>>>(x, aggm, W1l, W1r, b1, h);

    // Layer 2
    pq_kernel<<<(N_NODES * NCLS + 255) / 256, 256, 0, stream>>>(h, W2l, W2r, b2, pb, q);
    aggp_final_kernel<<<(N_NODES + 3) / 4, 256, 0, stream>>>(
        (const unsigned*)pb, q, offs, sorted_src, out);
}

// Round 6
// 182.238 us; speedup vs baseline: 3.9946x; 1.5176x over previous
//
#include <hip/hip_runtime.h>

// Problem constants (from reference)
#define N_NODES 100000
#define N_EDGES 1600000
#define D_IN    50
#define HIDDEN  128
#define NCLS    8

// Bucket-sort parameters
#define TILE    4096
#define NTILES  ((N_EDGES + TILE - 1) / TILE)   // 391
#define BSHIFT  9
#define NB      196                              // ceil(100000 / 512)

// LDS row stride (dwords) for padded bf16 weight rows: 128 bf16 + 8 pad = 136 bf16
#define LW 68

typedef __bf16 bf16_t;
typedef bf16_t bf16x8 __attribute__((ext_vector_type(8)));
typedef float  f32x4  __attribute__((ext_vector_type(4)));

// ---------------------------------------------------------------------------
// Helpers: bf16 pack/unpack (RNE)
// ---------------------------------------------------------------------------
__device__ __forceinline__ unsigned f2bf(float f) {
    union { float f; unsigned u; } a; a.f = f;
    unsigned u = a.u;
    return (u + 0x7FFFu + ((u >> 16) & 1u)) >> 16;
}
__device__ __forceinline__ unsigned pack2(float a, float b) {
    return f2bf(a) | (f2bf(b) << 16);
}
__device__ __forceinline__ float bf_lo(unsigned v) { return __uint_as_float(v << 16); }
__device__ __forceinline__ float bf_hi(unsigned v) { return __uint_as_float(v & 0xFFFF0000u); }

// ===========================================================================
// conv_x: xb[n][25] packed bf16 pairs; Acat x-part (cols 50..99) + zero pad.
// t = n*32 + j: j<25 -> pair j; j>=25 -> two zero dwords of the pad.
// ===========================================================================
__global__ __launch_bounds__(256) void conv_x_kernel(
    const float* __restrict__ x, unsigned* __restrict__ xb,
    unsigned* __restrict__ acat)
{
    int t = blockIdx.x * 256 + threadIdx.x;
    if (t >= N_NODES * 32) return;
    int n = t >> 5, j = t & 31;
    if (j < 25) {
        float2 v = ((const float2*)x)[n * 25 + j];
        unsigned pk = pack2(v.x, v.y);
        xb[n * 25 + j] = pk;
        acat[(size_t)n * 64 + 25 + j] = pk;
    } else {
        int z = n * 64 + 50 + (j - 25) * 2;
        acat[z] = 0u;
        acat[z + 1] = 0u;
    }
}

// ===========================================================================
// conv_w: W1cat^T [128][128] bf16 (k<50: W1l, k<100: W1r, else 0) and
//         W2cat^T [16][128] bf16 (n2<8: W2l col n2, else W2r col n2-8).
// ===========================================================================
__global__ __launch_bounds__(256) void conv_w_kernel(
    const float* __restrict__ W1l, const float* __restrict__ W1r,
    const float* __restrict__ W2l, const float* __restrict__ W2r,
    unsigned* __restrict__ Wt1g, unsigned* __restrict__ W2tg)
{
    int t = blockIdx.x * 256 + threadIdx.x;
    if (t < 8192) {
        int n = t >> 6, kp = t & 63;
        int k0 = kp * 2, k1 = k0 + 1;
        float v0 = (k0 < 50) ? W1l[k0 * 128 + n] : ((k0 < 100) ? W1r[(k0 - 50) * 128 + n] : 0.0f);
        float v1 = (k1 < 50) ? W1l[k1 * 128 + n] : ((k1 < 100) ? W1r[(k1 - 50) * 128 + n] : 0.0f);
        Wt1g[t] = pack2(v0, v1);
    } else if (t < 8192 + 1024) {
        int u = t - 8192;
        int n2 = u >> 6, kp = u & 63;
        int k0 = kp * 2;
        float v0 = (n2 < 8) ? W2l[k0 * 8 + n2] : W2r[k0 * 8 + n2 - 8];
        float v1 = (n2 < 8) ? W2l[(k0 + 1) * 8 + n2] : W2r[(k0 + 1) * 8 + n2 - 8];
        W2tg[u] = pack2(v0, v1);
    }
}

// ===========================================================================
// passA: per-tile bucket histogram (LDS atomics), g_hist[tile][NB]
// ===========================================================================
__global__ __launch_bounds__(256) void passA_kernel(
    const int* __restrict__ dst, int* __restrict__ g_hist)
{
    __shared__ int lh[NB];
    int tid = threadIdx.x;
    for (int i = tid; i < NB; i += 256) lh[i] = 0;
    __syncthreads();
    int base = blockIdx.x * TILE;
    int cnt = min(TILE, N_EDGES - base);
    for (int i = tid; i < cnt; i += 256)
        atomicAdd(&lh[dst[base + i] >> BSHIFT], 1);
    __syncthreads();
    for (int i = tid; i < NB; i += 256) g_hist[blockIdx.x * NB + i] = lh[i];
}

// ===========================================================================
// passB: per-bucket exclusive scan over tiles; btot[b] = bucket total
// ===========================================================================
__global__ __launch_bounds__(512) void passB_kernel(
    int* __restrict__ g_hist, int* __restrict__ btot)
{
    __shared__ int s[512];
    int b = blockIdx.x, tid = threadIdx.x;
    int v = (tid < NTILES) ? g_hist[tid * NB + b] : 0;
    s[tid] = v;
    __syncthreads();
    for (int d = 1; d < 512; d <<= 1) {
        int t = (tid >= d) ? s[tid - d] : 0;
        __syncthreads();
        s[tid] += t;
        __syncthreads();
    }
    if (tid < NTILES) g_hist[tid * NB + b] = s[tid] - v;
    if (tid == 511) btot[b] = s[511];
}

// ===========================================================================
// passB2: exclusive scan of btot -> bbase; sentinel offs[N] = E
// ===========================================================================
__global__ __launch_bounds__(256) void passB2_kernel(
    const int* __restrict__ btot, int* __restrict__ bbase, int* __restrict__ offs)
{
    __shared__ int s[256];
    int tid = threadIdx.x;
    int v = (tid < NB) ? btot[tid] : 0;
    s[tid] = v;
    __syncthreads();
    for (int d = 1; d < 256; d <<= 1) {
        int t = (tid >= d) ? s[tid - d] : 0;
        __syncthreads();
        s[tid] += t;
        __syncthreads();
    }
    if (tid < NB) bbase[tid] = s[tid] - v;
    if (tid == 0) offs[N_NODES] = N_EDGES;
}

// ===========================================================================
// passC: reorder tile by bucket in LDS, coalesced flush to bk_src/bk_dst
// ===========================================================================
__global__ __launch_bounds__(256) void passC_kernel(
    const int* __restrict__ src, const int* __restrict__ dst,
    const int* __restrict__ g_hist, const int* __restrict__ bbase,
    int* __restrict__ bk_src, int* __restrict__ bk_dst)
{
    __shared__ int hist[NB];
    __shared__ int seg[NB];
    __shared__ int cur[NB];
    __shared__ int gof[NB];
    __shared__ int sc[256];
    __shared__ int s_src[TILE];
    __shared__ int s_dst[TILE];
    __shared__ unsigned short s_bkt[TILE];

    int tid = threadIdx.x, tile = blockIdx.x;
    int base = tile * TILE;
    int cnt = min(TILE, N_EDGES - base);

    for (int i = tid; i < NB; i += 256) {
        hist[i] = 0;
        gof[i] = g_hist[tile * NB + i] + bbase[i];
    }
    __syncthreads();

    int es[16], ed[16];
    #pragma unroll
    for (int k = 0; k < 16; ++k) {
        int i = tid + k * 256;
        if (i < cnt) {
            es[k] = src[base + i];
            ed[k] = dst[base + i];
            atomicAdd(&hist[ed[k] >> BSHIFT], 1);
        }
    }
    __syncthreads();

    {
        int v = (tid < NB) ? hist[tid] : 0;
        sc[tid] = v;
        __syncthreads();
        for (int d = 1; d < 256; d <<= 1) {
            int t = (tid >= d) ? sc[tid - d] : 0;
            __syncthreads();
            sc[tid] += t;
            __syncthreads();
        }
        if (tid < NB) { seg[tid] = sc[tid] - v; cur[tid] = sc[tid] - v; }
    }
    __syncthreads();

    #pragma unroll
    for (int k = 0; k < 16; ++k) {
        int i = tid + k * 256;
        if (i < cnt) {
            int b = ed[k] >> BSHIFT;
            int p = atomicAdd(&cur[b], 1);
            s_src[p] = es[k];
            s_dst[p] = ed[k];
            s_bkt[p] = (unsigned short)b;
        }
    }
    __syncthreads();

    for (int i = tid; i < cnt; i += 256) {
        int b = s_bkt[i];
        int g = gof[b] + (i - seg[b]);
        bk_src[g] = s_src[i];
        bk_dst[g] = s_dst[i];
    }
}

// ===========================================================================
// passD: per-bucket CSR finalize: degree hist -> scan -> offs[] ->
// LDS-cursor scatter of sorted_src within the bucket's window.
// ===========================================================================
__global__ __launch_bounds__(512) void passD_kernel(
    const int* __restrict__ bk_src, const int* __restrict__ bk_dst,
    const int* __restrict__ bbase, const int* __restrict__ btot,
    int* __restrict__ sorted_src, int* __restrict__ offs)
{
    __shared__ int ldeg[512];
    __shared__ int lofs[512];
    int b = blockIdx.x, tid = threadIdx.x;
    int ebase = bbase[b];
    int ecnt = btot[b];
    int nbase = b << BSHIFT;

    ldeg[tid] = 0;
    __syncthreads();
    for (int i = tid; i < ecnt; i += 512)
        atomicAdd(&ldeg[bk_dst[ebase + i] - nbase], 1);
    __syncthreads();

    int v = ldeg[tid];
    lofs[tid] = v;
    __syncthreads();
    for (int d = 1; d < 512; d <<= 1) {
        int t = (tid >= d) ? lofs[tid - d] : 0;
        __syncthreads();
        lofs[tid] += t;
        __syncthreads();
    }
    int ex = lofs[tid] - v;

    int node = nbase + tid;
    if (node < N_NODES) offs[node] = ebase + ex;

    ldeg[tid] = ex;
    __syncthreads();
    for (int i = tid; i < ecnt; i += 512) {
        int dl = bk_dst[ebase + i] - nbase;
        int p = atomicAdd(&ldeg[dl], 1);
        sorted_src[ebase + p] = bk_src[ebase + i];
    }
}

// ===========================================================================
// Gather-aggregate bf16 x rows (mean folded in); writes packed bf16 means
// into Acat cols 0..49 (dwords 0..24).
// ===========================================================================
__global__ __launch_bounds__(256) void agg_x_kernel(
    const unsigned* __restrict__ xb,
    const int*      __restrict__ offs,
    const int*      __restrict__ ss,
    unsigned* __restrict__ acat)
{
    int node = blockIdx.x * 4 + (threadIdx.x >> 6);
    int lane = threadIdx.x & 63;
    int par = lane >> 5;
    int dw  = lane & 31;
    if (node >= N_NODES) return;
    int beg = offs[node], end = offs[node + 1];
    float2 acc = make_float2(0.0f, 0.0f);
    int i = beg + par;
    int sNext = (i < end) ? ss[i] : 0;
    for (; i < end; i += 2) {
        int s = sNext;
        int i2 = i + 2;
        sNext = (i2 < end) ? ss[i2] : 0;
        if (dw < 25) {
            unsigned v = xb[s * 25 + dw];
            acc.x += bf_lo(v);
            acc.y += bf_hi(v);
        }
    }
    acc.x += __shfl_xor(acc.x, 32);
    acc.y += __shfl_xor(acc.y, 32);
    if (par == 0 && dw < 25) {
        float inv = 1.0f / fmaxf((float)(end - beg), 1.0f);
        acat[(size_t)node * 64 + dw] = pack2(acc.x * inv, acc.y * inv);
    }
}

// ===========================================================================
// Fused MLP: h = relu(Acat @ W1cat + b1) (MFMA, swapped operands so lane
// holds one node), then p = bf16(h@W2l), q = h@W2r + b2 via a second MFMA
// pass through per-wave LDS. h never touches global memory.
// ===========================================================================
__global__ __launch_bounds__(256) void fused_mlp_kernel(
    const unsigned* __restrict__ Acat,   // [N][64] dwords (128 bf16)
    const unsigned* __restrict__ Wt1g,   // [128][64] dwords
    const unsigned* __restrict__ W2tg,   // [16][64] dwords
    const float* __restrict__ b1,
    const float* __restrict__ b2,
    unsigned* __restrict__ pb,           // [N][4] dwords (8 bf16)
    float* __restrict__ q)               // [N][8]
{
    __shared__ unsigned sWt[128 * LW];        // 34816 B
    __shared__ unsigned sW2t[16 * LW];        // 4352 B
    __shared__ bf16_t   sH[4][16 * 136];      // 17408 B

    int tid = threadIdx.x;
    for (int t = tid; t < 128 * 64; t += 256)
        sWt[(t >> 6) * LW + (t & 63)] = Wt1g[t];
    for (int t = tid; t < 16 * 64; t += 256)
        sW2t[(t >> 6) * LW + (t & 63)] = W2tg[t];
    __syncthreads();

    const int w    = tid >> 6;
    const int lane = tid & 63;
    const int lo   = lane & 15;
    const int g    = lane >> 4;

    // bias fragments (feature n = nt*16 + g*4 + r for C-rows)
    float b1v[8][4];
    #pragma unroll
    for (int nt = 0; nt < 8; ++nt)
        #pragma unroll
        for (int r = 0; r < 4; ++r)
            b1v[nt][r] = b1[nt * 16 + g * 4 + r];
    float b2v[4];
    #pragma unroll
    for (int r = 0; r < 4; ++r)
        b2v[r] = (g >= 2) ? b2[(g - 2) * 4 + r] : 0.0f;

    bf16_t* myH = &sH[w][0];

    for (int tile = blockIdx.x; tile * 64 < N_NODES; tile += gridDim.x) {
        int node = tile * 64 + w * 16 + lo;
        int nclamp = min(node, N_NODES - 1);

        // B-fragments: Acat row, 16B per (kstep, lane-group)
        int4 bi[4];
        #pragma unroll
        for (int ks = 0; ks < 4; ++ks)
            bi[ks] = *((const int4*)(Acat + (size_t)nclamp * 64 + ks * 16 + g * 4));

        // GEMM1: acc[nt] = W1cat^T(ntile) x Acat-row -> h^T fragments
        f32x4 acc[8];
        #pragma unroll
        for (int nt = 0; nt < 8; ++nt) acc[nt] = (f32x4)0.0f;
        #pragma unroll
        for (int nt = 0; nt < 8; ++nt) {
            #pragma unroll
            for (int ks = 0; ks < 4; ++ks) {
                int4 ai = *((const int4*)(sWt + (nt * 16 + lo) * LW + ks * 16 + g * 4));
                acc[nt] = __builtin_amdgcn_mfma_f32_16x16x32_bf16(
                    __builtin_bit_cast(bf16x8, ai),
                    __builtin_bit_cast(bf16x8, bi[ks]), acc[nt], 0, 0, 0);
            }
        }

        // bias + relu + bf16, stage h into per-wave LDS: sH[row=node_lo][feat]
        #pragma unroll
        for (int nt = 0; nt < 8; ++nt) {
            union { bf16_t h[4]; uint2 u; } pk;
            #pragma unroll
            for (int r = 0; r < 4; ++r)
                pk.h[r] = (bf16_t)fmaxf(acc[nt][r] + b1v[nt][r], 0.0f);
            *((uint2*)(myH + lo * 136 + nt * 16 + g * 4)) = pk.u;
        }
        __syncthreads();   // cross-lane h exchange (per-wave region; orders LDS)

        // GEMM2: pq^T = W2cat^T x h-row
        f32x4 acc2 = (f32x4)0.0f;
        #pragma unroll
        for (int ks = 0; ks < 4; ++ks) {
            int4 a2 = *((const int4*)(sW2t + lo * LW + ks * 16 + g * 4));
            int4 h2 = *((const int4*)(myH + lo * 136 + ks * 32 + g * 8));
            acc2 = __builtin_amdgcn_mfma_f32_16x16x32_bf16(
                __builtin_bit_cast(bf16x8, a2),
                __builtin_bit_cast(bf16x8, h2), acc2, 0, 0, 0);
        }

        if (node < N_NODES) {
            if (g < 2) {
                // p features 4g..4g+3 as bf16
                union { bf16_t h[4]; uint2 u; } pk;
                #pragma unroll
                for (int r = 0; r < 4; ++r) pk.h[r] = (bf16_t)acc2[r];
                *((uint2*)(pb + (size_t)node * 4 + g * 2)) = pk.u;
            } else {
                float4 qq;
                qq.x = acc2[0] + b2v[0];
                qq.y = acc2[1] + b2v[1];
                qq.z = acc2[2] + b2v[2];
                qq.w = acc2[3] + b2v[3];
                *((float4*)(q + (size_t)node * 8 + (g - 2) * 4)) = qq;
            }
        }
        __syncthreads();   // protect sH before next iteration's writes
    }
}

// ===========================================================================
// Gather-aggregate bf16 p rows + final: out = (sum p[src]) / max(deg,1) + q
// ===========================================================================
__global__ __launch_bounds__(256) void aggp_final_kernel(
    const unsigned* __restrict__ pb,   // [N][4] dwords (8 bf16)
    const float*    __restrict__ q,
    const int*      __restrict__ offs,
    const int*      __restrict__ ss,
    float* __restrict__ out)
{
    int node = blockIdx.x * 4 + (threadIdx.x >> 6);
    int lane = threadIdx.x & 63;
    int k  = lane >> 2;
    int c2 = lane & 3;
    if (node >= N_NODES) return;
    int beg = offs[node], end = offs[node + 1];
    float2 acc = make_float2(0.0f, 0.0f);
    int i = beg + k;
    int sNext = (i < end) ? ss[i] : 0;
    for (; i < end; i += 16) {
        int s = sNext;
        int i2 = i + 16;
        sNext = (i2 < end) ? ss[i2] : 0;
        unsigned v = pb[s * 4 + c2];
        acc.x += bf_lo(v);
        acc.y += bf_hi(v);
    }
    acc.x += __shfl_xor(acc.x, 4);  acc.y += __shfl_xor(acc.y, 4);
    acc.x += __shfl_xor(acc.x, 8);  acc.y += __shfl_xor(acc.y, 8);
    acc.x += __shfl_xor(acc.x, 16); acc.y += __shfl_xor(acc.y, 16);
    acc.x += __shfl_xor(acc.x, 32); acc.y += __shfl_xor(acc.y, 32);
    if (lane < 4) {
        float inv = 1.0f / fmaxf((float)(end - beg), 1.0f);
        float2 qq = ((const float2*)(q + (size_t)node * NCLS))[c2];
        ((float2*)(out + (size_t)node * NCLS))[c2] =
            make_float2(acc.x * inv + qq.x, acc.y * inv + qq.y);
    }
}

// ===========================================================================
extern "C" void kernel_launch(void* const* d_in, const int* in_sizes, int n_in,
                              void* d_out, int out_size, void* d_ws, size_t ws_size,
                              hipStream_t stream)
{
    const float* x   = (const float*)d_in[0];
    const int*   ei  = (const int*)  d_in[1];
    const float* W1l = (const float*)d_in[2];
    const float* W1r = (const float*)d_in[3];
    const float* b1  = (const float*)d_in[4];
    const float* W2l = (const float*)d_in[5];
    const float* W2r = (const float*)d_in[6];
    const float* b2  = (const float*)d_in[7];
    float* out = (float*)d_out;

    const int* src = ei;
    const int* dst = ei + N_EDGES;

    // Workspace layout (dword units; all segment sizes are multiples of 4)
    int* ws = (int*)d_ws;
    int*      offs       = ws;                                   // 100004
    int*      g_hist     = offs + (N_NODES + 4);                 // 76636
    int*      btot       = g_hist + NTILES * NB;                 // 256
    int*      bbase      = btot + 256;                           // 256
    int*      sorted_src = bbase + 256;                          // E
    unsigned* xb         = (unsigned*)(sorted_src + N_EDGES);    // N*25
    unsigned* Acat       = xb + (size_t)N_NODES * 25;            // N*64
    unsigned* Wt1g       = Acat + (size_t)N_NODES * 64;          // 8192
    unsigned* W2tg       = Wt1g + 8192;                          // 1024
    unsigned* pb         = W2tg + 1024;                          // N*4
    float*    q          = (float*)(pb + (size_t)N_NODES * 4);   // N*8
    int*      bk_src     = (int*)(q + (size_t)N_NODES * 8);      // E
    int*      bk_dst     = bk_src + N_EDGES;                     // E

    // x -> bf16 (xb compact for gather; Acat cols 50..99 + zero pad)
    conv_x_kernel<<<(N_NODES * 32 + 255) / 256, 256, 0, stream>>>(x, xb, Acat);
    // weights -> transposed bf16
    conv_w_kernel<<<36, 256, 0, stream>>>(W1l, W1r, W2l, W2r, Wt1g, W2tg);

    // CSR build via two-level bucket sort
    passA_kernel <<<NTILES, 256, 0, stream>>>(dst, g_hist);
    passB_kernel <<<NB, 512, 0, stream>>>(g_hist, btot);
    passB2_kernel<<<1, 256, 0, stream>>>(btot, bbase, offs);
    passC_kernel <<<NTILES, 256, 0, stream>>>(src, dst, g_hist, bbase, bk_src, bk_dst);
    passD_kernel <<<NB, 512, 0, stream>>>(bk_src, bk_dst, bbase, btot, sorted_src, offs);

    // Layer 1 aggregation (writes Acat cols 0..49)
    agg_x_kernel<<<(N_NODES + 3) / 4, 256, 0, stream>>>(xb, offs, sorted_src, Acat);

    // Fused layer1 GEMM + relu + layer2 GEMMs (h stays on-chip)
    fused_mlp_kernel<<<512, 256, 0, stream>>>(Acat, Wt1g, W2tg, b1, b2, pb, q);

    // Layer 2 aggregation + final
    aggp_final_kernel<<<(N_NODES + 3) / 4, 256, 0, stream>>>(
        (const unsigned*)pb, q, offs, sorted_src, out);
}

// Round 7
// 142.484 us; speedup vs baseline: 5.1091x; 1.2790x over previous
//
#include <hip/hip_runtime.h>

// Problem constants (from reference)
#define N_NODES 100000
#define N_EDGES 1600000
#define D_IN    50
#define HIDDEN  128
#define NCLS    8

// Bucket-sort parameters
#define TILE    4096
#define NTILES  ((N_EDGES + TILE - 1) / TILE)   // 391
#define BSHIFT  9
#define NB      196                              // ceil(100000 / 512)

// LDS row stride (dwords) for padded bf16 weight rows: 128 bf16 + 8 pad = 136 bf16
#define LW 68

typedef __bf16 bf16_t;
typedef bf16_t bf16x8 __attribute__((ext_vector_type(8)));
typedef float  f32x4  __attribute__((ext_vector_type(4)));

// ---------------------------------------------------------------------------
// Helpers: bf16 pack/unpack (RNE)
// ---------------------------------------------------------------------------
__device__ __forceinline__ unsigned f2bf(float f) {
    union { float f; unsigned u; } a; a.f = f;
    unsigned u = a.u;
    return (u + 0x7FFFu + ((u >> 16) & 1u)) >> 16;
}
__device__ __forceinline__ unsigned pack2(float a, float b) {
    return f2bf(a) | (f2bf(b) << 16);
}
__device__ __forceinline__ float bf_lo(unsigned v) { return __uint_as_float(v << 16); }
__device__ __forceinline__ float bf_hi(unsigned v) { return __uint_as_float(v & 0xFFFF0000u); }

// ===========================================================================
// conv_x: xb[n][25] packed bf16 pairs; Acat x-part (cols 50..99) + zero pad.
// ===========================================================================
__global__ __launch_bounds__(256) void conv_x_kernel(
    const float* __restrict__ x, unsigned* __restrict__ xb,
    unsigned* __restrict__ acat)
{
    int t = blockIdx.x * 256 + threadIdx.x;
    if (t >= N_NODES * 32) return;
    int n = t >> 5, j = t & 31;
    if (j < 25) {
        float2 v = ((const float2*)x)[n * 25 + j];
        unsigned pk = pack2(v.x, v.y);
        xb[n * 25 + j] = pk;
        acat[(size_t)n * 64 + 25 + j] = pk;
    } else {
        int z = n * 64 + 50 + (j - 25) * 2;
        acat[z] = 0u;
        acat[z + 1] = 0u;
    }
}

// ===========================================================================
// conv_w: W1cat^T [128][128] bf16 and W2cat^T [16][128] bf16
// ===========================================================================
__global__ __launch_bounds__(256) void conv_w_kernel(
    const float* __restrict__ W1l, const float* __restrict__ W1r,
    const float* __restrict__ W2l, const float* __restrict__ W2r,
    unsigned* __restrict__ Wt1g, unsigned* __restrict__ W2tg)
{
    int t = blockIdx.x * 256 + threadIdx.x;
    if (t < 8192) {
        int n = t >> 6, kp = t & 63;
        int k0 = kp * 2, k1 = k0 + 1;
        float v0 = (k0 < 50) ? W1l[k0 * 128 + n] : ((k0 < 100) ? W1r[(k0 - 50) * 128 + n] : 0.0f);
        float v1 = (k1 < 50) ? W1l[k1 * 128 + n] : ((k1 < 100) ? W1r[(k1 - 50) * 128 + n] : 0.0f);
        Wt1g[t] = pack2(v0, v1);
    } else if (t < 8192 + 1024) {
        int u = t - 8192;
        int n2 = u >> 6, kp = u & 63;
        int k0 = kp * 2;
        float v0 = (n2 < 8) ? W2l[k0 * 8 + n2] : W2r[k0 * 8 + n2 - 8];
        float v1 = (n2 < 8) ? W2l[(k0 + 1) * 8 + n2] : W2r[(k0 + 1) * 8 + n2 - 8];
        W2tg[u] = pack2(v0, v1);
    }
}

// ===========================================================================
// passA: per-tile bucket histogram (LDS atomics), g_hist[tile][NB]
// ===========================================================================
__global__ __launch_bounds__(256) void passA_kernel(
    const int* __restrict__ dst, int* __restrict__ g_hist)
{
    __shared__ int lh[NB];
    int tid = threadIdx.x;
    for (int i = tid; i < NB; i += 256) lh[i] = 0;
    __syncthreads();
    int base = blockIdx.x * TILE;
    int cnt = min(TILE, N_EDGES - base);
    for (int i = tid; i < cnt; i += 256)
        atomicAdd(&lh[dst[base + i] >> BSHIFT], 1);
    __syncthreads();
    for (int i = tid; i < NB; i += 256) g_hist[blockIdx.x * NB + i] = lh[i];
}

// ===========================================================================
// passB: per-bucket exclusive scan over tiles; btot[b] = bucket total
// ===========================================================================
__global__ __launch_bounds__(512) void passB_kernel(
    int* __restrict__ g_hist, int* __restrict__ btot)
{
    __shared__ int s[512];
    int b = blockIdx.x, tid = threadIdx.x;
    int v = (tid < NTILES) ? g_hist[tid * NB + b] : 0;
    s[tid] = v;
    __syncthreads();
    for (int d = 1; d < 512; d <<= 1) {
        int t = (tid >= d) ? s[tid - d] : 0;
        __syncthreads();
        s[tid] += t;
        __syncthreads();
    }
    if (tid < NTILES) g_hist[tid * NB + b] = s[tid] - v;
    if (tid == 511) btot[b] = s[511];
}

// ===========================================================================
// passB2: exclusive scan of btot -> bbase; sentinel offs[N] = E
// ===========================================================================
__global__ __launch_bounds__(256) void passB2_kernel(
    const int* __restrict__ btot, int* __restrict__ bbase, int* __restrict__ offs)
{
    __shared__ int s[256];
    int tid = threadIdx.x;
    int v = (tid < NB) ? btot[tid] : 0;
    s[tid] = v;
    __syncthreads();
    for (int d = 1; d < 256; d <<= 1) {
        int t = (tid >= d) ? s[tid - d] : 0;
        __syncthreads();
        s[tid] += t;
        __syncthreads();
    }
    if (tid < NB) bbase[tid] = s[tid] - v;
    if (tid == 0) offs[N_NODES] = N_EDGES;
}

// ===========================================================================
// passC: reorder tile by bucket in LDS, coalesced flush to bk_src/bk_dst
// ===========================================================================
__global__ __launch_bounds__(256) void passC_kernel(
    const int* __restrict__ src, const int* __restrict__ dst,
    const int* __restrict__ g_hist, const int* __restrict__ bbase,
    int* __restrict__ bk_src, int* __restrict__ bk_dst)
{
    __shared__ int hist[NB];
    __shared__ int seg[NB];
    __shared__ int cur[NB];
    __shared__ int gof[NB];
    __shared__ int sc[256];
    __shared__ int s_src[TILE];
    __shared__ int s_dst[TILE];
    __shared__ unsigned short s_bkt[TILE];

    int tid = threadIdx.x, tile = blockIdx.x;
    int base = tile * TILE;
    int cnt = min(TILE, N_EDGES - base);

    for (int i = tid; i < NB; i += 256) {
        hist[i] = 0;
        gof[i] = g_hist[tile * NB + i] + bbase[i];
    }
    __syncthreads();

    int es[16], ed[16];
    #pragma unroll
    for (int k = 0; k < 16; ++k) {
        int i = tid + k * 256;
        if (i < cnt) {
            es[k] = src[base + i];
            ed[k] = dst[base + i];
            atomicAdd(&hist[ed[k] >> BSHIFT], 1);
        }
    }
    __syncthreads();

    {
        int v = (tid < NB) ? hist[tid] : 0;
        sc[tid] = v;
        __syncthreads();
        for (int d = 1; d < 256; d <<= 1) {
            int t = (tid >= d) ? sc[tid - d] : 0;
            __syncthreads();
            sc[tid] += t;
            __syncthreads();
        }
        if (tid < NB) { seg[tid] = sc[tid] - v; cur[tid] = sc[tid] - v; }
    }
    __syncthreads();

    #pragma unroll
    for (int k = 0; k < 16; ++k) {
        int i = tid + k * 256;
        if (i < cnt) {
            int b = ed[k] >> BSHIFT;
            int p = atomicAdd(&cur[b], 1);
            s_src[p] = es[k];
            s_dst[p] = ed[k];
            s_bkt[p] = (unsigned short)b;
        }
    }
    __syncthreads();

    for (int i = tid; i < cnt; i += 256) {
        int b = s_bkt[i];
        int g = gof[b] + (i - seg[b]);
        bk_src[g] = s_src[i];
        bk_dst[g] = s_dst[i];
    }
}

// ===========================================================================
// passD: per-bucket CSR finalize
// ===========================================================================
__global__ __launch_bounds__(512) void passD_kernel(
    const int* __restrict__ bk_src, const int* __restrict__ bk_dst,
    const int* __restrict__ bbase, const int* __restrict__ btot,
    int* __restrict__ sorted_src, int* __restrict__ offs)
{
    __shared__ int ldeg[512];
    __shared__ int lofs[512];
    int b = blockIdx.x, tid = threadIdx.x;
    int ebase = bbase[b];
    int ecnt = btot[b];
    int nbase = b << BSHIFT;

    ldeg[tid] = 0;
    __syncthreads();
    for (int i = tid; i < ecnt; i += 512)
        atomicAdd(&ldeg[bk_dst[ebase + i] - nbase], 1);
    __syncthreads();

    int v = ldeg[tid];
    lofs[tid] = v;
    __syncthreads();
    for (int d = 1; d < 512; d <<= 1) {
        int t = (tid >= d) ? lofs[tid - d] : 0;
        __syncthreads();
        lofs[tid] += t;
        __syncthreads();
    }
    int ex = lofs[tid] - v;

    int node = nbase + tid;
    if (node < N_NODES) offs[node] = ebase + ex;

    ldeg[tid] = ex;
    __syncthreads();
    for (int i = tid; i < ecnt; i += 512) {
        int dl = bk_dst[ebase + i] - nbase;
        int p = atomicAdd(&ldeg[dl], 1);
        sorted_src[ebase + p] = bk_src[ebase + i];
    }
}

// ===========================================================================
// Gather-aggregate bf16 x rows. One node per HALF-WAVE (8 nodes/block),
// 4-deep unrolled edge loop -> 8 row-gathers in flight per wave, no
// cross-lane reduction (each half-wave privately owns its node).
// ===========================================================================
__global__ __launch_bounds__(256) void agg_x_kernel(
    const unsigned* __restrict__ xb,
    const int*      __restrict__ offs,
    const int*      __restrict__ ss,
    unsigned* __restrict__ acat)
{
    int node = blockIdx.x * 8 + (threadIdx.x >> 5);
    int dw   = threadIdx.x & 31;
    if (node >= N_NODES) return;
    int beg = offs[node], end = offs[node + 1];
    float2 a0 = {0.f, 0.f}, a1 = {0.f, 0.f}, a2 = {0.f, 0.f}, a3 = {0.f, 0.f};
    int i = beg;
    for (; i + 3 < end; i += 4) {
        int s0 = ss[i], s1 = ss[i + 1], s2 = ss[i + 2], s3 = ss[i + 3];
        if (dw < 25) {
            unsigned v0 = xb[s0 * 25 + dw];
            unsigned v1 = xb[s1 * 25 + dw];
            unsigned v2 = xb[s2 * 25 + dw];
            unsigned v3 = xb[s3 * 25 + dw];
            a0.x += bf_lo(v0); a0.y += bf_hi(v0);
            a1.x += bf_lo(v1); a1.y += bf_hi(v1);
            a2.x += bf_lo(v2); a2.y += bf_hi(v2);
            a3.x += bf_lo(v3); a3.y += bf_hi(v3);
        }
    }
    for (; i < end; ++i) {
        int s = ss[i];
        if (dw < 25) {
            unsigned v = xb[s * 25 + dw];
            a0.x += bf_lo(v); a0.y += bf_hi(v);
        }
    }
    if (dw < 25) {
        float inv = 1.0f / fmaxf((float)(end - beg), 1.0f);
        acat[(size_t)node * 64 + dw] =
            pack2((a0.x + a1.x + a2.x + a3.x) * inv,
                  (a0.y + a1.y + a2.y + a3.y) * inv);
    }
}

// ===========================================================================
// Fused MLP: h = relu(Acat @ W1cat + b1) via MFMA (swapped operands), then
// p = bf16(h@W2l), q = h@W2r + b2 via a second MFMA pass through LDS.
// ===========================================================================
__global__ __launch_bounds__(256) void fused_mlp_kernel(
    const unsigned* __restrict__ Acat,   // [N][64] dwords (128 bf16)
    const unsigned* __restrict__ Wt1g,   // [128][64] dwords
    const unsigned* __restrict__ W2tg,   // [16][64] dwords
    const float* __restrict__ b1,
    const float* __restrict__ b2,
    unsigned* __restrict__ pb,           // [N][4] dwords (8 bf16)
    float* __restrict__ q)               // [N][8]
{
    __shared__ unsigned sWt[128 * LW];
    __shared__ unsigned sW2t[16 * LW];
    __shared__ bf16_t   sH[4][16 * 136];

    int tid = threadIdx.x;
    for (int t = tid; t < 128 * 64; t += 256)
        sWt[(t >> 6) * LW + (t & 63)] = Wt1g[t];
    for (int t = tid; t < 16 * 64; t += 256)
        sW2t[(t >> 6) * LW + (t & 63)] = W2tg[t];
    __syncthreads();

    const int w    = tid >> 6;
    const int lane = tid & 63;
    const int lo   = lane & 15;
    const int g    = lane >> 4;

    float b1v[8][4];
    #pragma unroll
    for (int nt = 0; nt < 8; ++nt)
        #pragma unroll
        for (int r = 0; r < 4; ++r)
            b1v[nt][r] = b1[nt * 16 + g * 4 + r];
    float b2v[4];
    #pragma unroll
    for (int r = 0; r < 4; ++r)
        b2v[r] = (g >= 2) ? b2[(g - 2) * 4 + r] : 0.0f;

    bf16_t* myH = &sH[w][0];

    for (int tile = blockIdx.x; tile * 64 < N_NODES; tile += gridDim.x) {
        int node = tile * 64 + w * 16 + lo;
        int nclamp = min(node, N_NODES - 1);

        int4 bi[4];
        #pragma unroll
        for (int ks = 0; ks < 4; ++ks)
            bi[ks] = *((const int4*)(Acat + (size_t)nclamp * 64 + ks * 16 + g * 4));

        f32x4 acc[8];
        #pragma unroll
        for (int nt = 0; nt < 8; ++nt) acc[nt] = (f32x4)0.0f;
        #pragma unroll
        for (int nt = 0; nt < 8; ++nt) {
            #pragma unroll
            for (int ks = 0; ks < 4; ++ks) {
                int4 ai = *((const int4*)(sWt + (nt * 16 + lo) * LW + ks * 16 + g * 4));
                acc[nt] = __builtin_amdgcn_mfma_f32_16x16x32_bf16(
                    __builtin_bit_cast(bf16x8, ai),
                    __builtin_bit_cast(bf16x8, bi[ks]), acc[nt], 0, 0, 0);
            }
        }

        #pragma unroll
        for (int nt = 0; nt < 8; ++nt) {
            union { bf16_t h[4]; uint2 u; } pk;
            #pragma unroll
            for (int r = 0; r < 4; ++r)
                pk.h[r] = (bf16_t)fmaxf(acc[nt][r] + b1v[nt][r], 0.0f);
            *((uint2*)(myH + lo * 136 + nt * 16 + g * 4)) = pk.u;
        }
        __syncthreads();

        f32x4 acc2 = (f32x4)0.0f;
        #pragma unroll
        for (int ks = 0; ks < 4; ++ks) {
            int4 a2 = *((const int4*)(sW2t + lo * LW + ks * 16 + g * 4));
            int4 h2 = *((const int4*)(myH + lo * 136 + ks * 32 + g * 8));
            acc2 = __builtin_amdgcn_mfma_f32_16x16x32_bf16(
                __builtin_bit_cast(bf16x8, a2),
                __builtin_bit_cast(bf16x8, h2), acc2, 0, 0, 0);
        }

        if (node < N_NODES) {
            if (g < 2) {
                union { bf16_t h[4]; uint2 u; } pk;
                #pragma unroll
                for (int r = 0; r < 4; ++r) pk.h[r] = (bf16_t)acc2[r];
                *((uint2*)(pb + (size_t)node * 4 + g * 2)) = pk.u;
            } else {
                float4 qq;
                qq.x = acc2[0] + b2v[0];
                qq.y = acc2[1] + b2v[1];
                qq.z = acc2[2] + b2v[2];
                qq.w = acc2[3] + b2v[3];
                *((float4*)(q + (size_t)node * 8 + (g - 2) * 4)) = qq;
            }
        }
        __syncthreads();
    }
}

// ===========================================================================
// Gather-aggregate bf16 p rows + final: out = (sum p[src]) / max(deg,1) + q
// ===========================================================================
__global__ __launch_bounds__(256) void aggp_final_kernel(
    const unsigned* __restrict__ pb,   // [N][4] dwords (8 bf16)
    const float*    __restrict__ q,
    const int*      __restrict__ offs,
    const int*      __restrict__ ss,
    float* __restrict__ out)
{
    int node = blockIdx.x * 4 + (threadIdx.x >> 6);
    int lane = threadIdx.x & 63;
    int k  = lane >> 2;
    int c2 = lane & 3;
    if (node >= N_NODES) return;
    int beg = offs[node], end = offs[node + 1];
    float2 acc = make_float2(0.0f, 0.0f);
    int i = beg + k;
    int sNext = (i < end) ? ss[i] : 0;
    for (; i < end; i += 16) {
        int s = sNext;
        int i2 = i + 16;
        sNext = (i2 < end) ? ss[i2] : 0;
        unsigned v = pb[s * 4 + c2];
        acc.x += bf_lo(v);
        acc.y += bf_hi(v);
    }
    acc.x += __shfl_xor(acc.x, 4);  acc.y += __shfl_xor(acc.y, 4);
    acc.x += __shfl_xor(acc.x, 8);  acc.y += __shfl_xor(acc.y, 8);
    acc.x += __shfl_xor(acc.x, 16); acc.y += __shfl_xor(acc.y, 16);
    acc.x += __shfl_xor(acc.x, 32); acc.y += __shfl_xor(acc.y, 32);
    if (lane < 4) {
        float inv = 1.0f / fmaxf((float)(end - beg), 1.0f);
        float2 qq = ((const float2*)(q + (size_t)node * NCLS))[c2];
        ((float2*)(out + (size_t)node * NCLS))[c2] =
            make_float2(acc.x * inv + qq.x, acc.y * inv + qq.y);
    }
}

// ===========================================================================
extern "C" void kernel_launch(void* const* d_in, const int* in_sizes, int n_in,
                              void* d_out, int out_size, void* d_ws, size_t ws_size,
                              hipStream_t stream)
{
    const float* x   = (const float*)d_in[0];
    const int*   ei  = (const int*)  d_in[1];
    const float* W1l = (const float*)d_in[2];
    const float* W1r = (const float*)d_in[3];
    const float* b1  = (const float*)d_in[4];
    const float* W2l = (const float*)d_in[5];
    const float* W2r = (const float*)d_in[6];
    const float* b2  = (const float*)d_in[7];
    float* out = (float*)d_out;

    const int* src = ei;
    const int* dst = ei + N_EDGES;

    // Workspace layout (dword units; all segment sizes are multiples of 4)
    int* ws = (int*)d_ws;
    int*      offs       = ws;                                   // 100004
    int*      g_hist     = offs + (N_NODES + 4);                 // 76636
    int*      btot       = g_hist + NTILES * NB;                 // 256
    int*      bbase      = btot + 256;                           // 256
    int*      sorted_src = bbase + 256;                          // E
    unsigned* xb         = (unsigned*)(sorted_src + N_EDGES);    // N*25
    unsigned* Acat       = xb + (size_t)N_NODES * 25;            // N*64
    unsigned* Wt1g       = Acat + (size_t)N_NODES * 64;          // 8192
    unsigned* W2tg       = Wt1g + 8192;                          // 1024
    unsigned* pb         = W2tg + 1024;                          // N*4
    float*    q          = (float*)(pb + (size_t)N_NODES * 4);   // N*8
    int*      bk_src     = (int*)(q + (size_t)N_NODES * 8);      // E
    int*      bk_dst     = bk_src + N_EDGES;                     // E

    conv_x_kernel<<<(N_NODES * 32 + 255) / 256, 256, 0, stream>>>(x, xb, Acat);
    conv_w_kernel<<<36, 256, 0, stream>>>(W1l, W1r, W2l, W2r, Wt1g, W2tg);

    // CSR build via two-level bucket sort
    passA_kernel <<<NTILES, 256, 0, stream>>>(dst, g_hist);
    passB_kernel <<<NB, 512, 0, stream>>>(g_hist, btot);
    passB2_kernel<<<1, 256, 0, stream>>>(btot, bbase, offs);
    passC_kernel <<<NTILES, 256, 0, stream>>>(src, dst, g_hist, bbase, bk_src, bk_dst);
    passD_kernel <<<NB, 512, 0, stream>>>(bk_src, bk_dst, bbase, btot, sorted_src, offs);

    // Layer 1 aggregation (writes Acat cols 0..49)
    agg_x_kernel<<<(N_NODES + 7) / 8, 256, 0, stream>>>(xb, offs, sorted_src, Acat);

    // Fused layer1 GEMM + relu + layer2 GEMMs (h stays on-chip)
    fused_mlp_kernel<<<512, 256, 0, stream>>>(Acat, Wt1g, W2tg, b1, b2, pb, q);

    // Layer 2 aggregation + final
    aggp_final_kernel<<<(N_NODES + 3) / 4, 256, 0, stream>>>(
        (const unsigned*)pb, q, offs, sorted_src, out);
}

// Round 8
// 133.944 us; speedup vs baseline: 5.4349x; 1.0638x over previous
//
#include <hip/hip_runtime.h>

// Problem constants (from reference)
#define N_NODES 100000
#define N_EDGES 1600000
#define D_IN    50
#define HIDDEN  128
#define NCLS    8

// Bucket-sort parameters
#define TILE    4096
#define NTILES  ((N_EDGES + TILE - 1) / TILE)   // 391
#define BSHIFT  9
#define NB      196                              // ceil(100000 / 512)

// LDS row stride (dwords) for padded bf16 weight rows: 128 bf16 + 8 pad = 136 bf16
#define LW 68

typedef __bf16 bf16_t;
typedef bf16_t bf16x8 __attribute__((ext_vector_type(8)));
typedef float  f32x4  __attribute__((ext_vector_type(4)));

// ---------------------------------------------------------------------------
// Helpers: bf16 pack/unpack (RNE)
// ---------------------------------------------------------------------------
__device__ __forceinline__ unsigned f2bf(float f) {
    union { float f; unsigned u; } a; a.f = f;
    unsigned u = a.u;
    return (u + 0x7FFFu + ((u >> 16) & 1u)) >> 16;
}
__device__ __forceinline__ unsigned pack2(float a, float b) {
    return f2bf(a) | (f2bf(b) << 16);
}
__device__ __forceinline__ float bf_lo(unsigned v) { return __uint_as_float(v << 16); }
__device__ __forceinline__ float bf_hi(unsigned v) { return __uint_as_float(v & 0xFFFF0000u); }

// ===========================================================================
// conv_x: xb[n][25] packed bf16 pairs; Acat x-part (cols 50..99) + zero pad.
// ===========================================================================
__global__ __launch_bounds__(256) void conv_x_kernel(
    const float* __restrict__ x, unsigned* __restrict__ xb,
    unsigned* __restrict__ acat)
{
    int t = blockIdx.x * 256 + threadIdx.x;
    if (t >= N_NODES * 32) return;
    int n = t >> 5, j = t & 31;
    if (j < 25) {
        float2 v = ((const float2*)x)[n * 25 + j];
        unsigned pk = pack2(v.x, v.y);
        xb[n * 25 + j] = pk;
        acat[(size_t)n * 64 + 25 + j] = pk;
    } else {
        int z = n * 64 + 50 + (j - 25) * 2;
        acat[z] = 0u;
        acat[z + 1] = 0u;
    }
}

// ===========================================================================
// conv_w: W1cat^T [128][128] bf16 and W2cat^T [16][128] bf16
// ===========================================================================
__global__ __launch_bounds__(256) void conv_w_kernel(
    const float* __restrict__ W1l, const float* __restrict__ W1r,
    const float* __restrict__ W2l, const float* __restrict__ W2r,
    unsigned* __restrict__ Wt1g, unsigned* __restrict__ W2tg)
{
    int t = blockIdx.x * 256 + threadIdx.x;
    if (t < 8192) {
        int n = t >> 6, kp = t & 63;
        int k0 = kp * 2, k1 = k0 + 1;
        float v0 = (k0 < 50) ? W1l[k0 * 128 + n] : ((k0 < 100) ? W1r[(k0 - 50) * 128 + n] : 0.0f);
        float v1 = (k1 < 50) ? W1l[k1 * 128 + n] : ((k1 < 100) ? W1r[(k1 - 50) * 128 + n] : 0.0f);
        Wt1g[t] = pack2(v0, v1);
    } else if (t < 8192 + 1024) {
        int u = t - 8192;
        int n2 = u >> 6, kp = u & 63;
        int k0 = kp * 2;
        float v0 = (n2 < 8) ? W2l[k0 * 8 + n2] : W2r[k0 * 8 + n2 - 8];
        float v1 = (n2 < 8) ? W2l[(k0 + 1) * 8 + n2] : W2r[(k0 + 1) * 8 + n2 - 8];
        W2tg[u] = pack2(v0, v1);
    }
}

// ===========================================================================
// passA: per-tile bucket histogram (LDS atomics), g_hist[tile][NB]
// ===========================================================================
__global__ __launch_bounds__(256) void passA_kernel(
    const int* __restrict__ dst, int* __restrict__ g_hist)
{
    __shared__ int lh[NB];
    int tid = threadIdx.x;
    for (int i = tid; i < NB; i += 256) lh[i] = 0;
    __syncthreads();
    int base = blockIdx.x * TILE;
    int cnt = min(TILE, N_EDGES - base);
    for (int i = tid; i < cnt; i += 256)
        atomicAdd(&lh[dst[base + i] >> BSHIFT], 1);
    __syncthreads();
    for (int i = tid; i < NB; i += 256) g_hist[blockIdx.x * NB + i] = lh[i];
}

// ===========================================================================
// passB: per-bucket exclusive scan over tiles; btot[b] = bucket total
// ===========================================================================
__global__ __launch_bounds__(512) void passB_kernel(
    int* __restrict__ g_hist, int* __restrict__ btot)
{
    __shared__ int s[512];
    int b = blockIdx.x, tid = threadIdx.x;
    int v = (tid < NTILES) ? g_hist[tid * NB + b] : 0;
    s[tid] = v;
    __syncthreads();
    for (int d = 1; d < 512; d <<= 1) {
        int t = (tid >= d) ? s[tid - d] : 0;
        __syncthreads();
        s[tid] += t;
        __syncthreads();
    }
    if (tid < NTILES) g_hist[tid * NB + b] = s[tid] - v;
    if (tid == 511) btot[b] = s[511];
}

// ===========================================================================
// passB2: exclusive scan of btot -> bbase; sentinel offs[N] = E
// ===========================================================================
__global__ __launch_bounds__(256) void passB2_kernel(
    const int* __restrict__ btot, int* __restrict__ bbase, int* __restrict__ offs)
{
    __shared__ int s[256];
    int tid = threadIdx.x;
    int v = (tid < NB) ? btot[tid] : 0;
    s[tid] = v;
    __syncthreads();
    for (int d = 1; d < 256; d <<= 1) {
        int t = (tid >= d) ? s[tid - d] : 0;
        __syncthreads();
        s[tid] += t;
        __syncthreads();
    }
    if (tid < NB) bbase[tid] = s[tid] - v;
    if (tid == 0) offs[N_NODES] = N_EDGES;
}

// ===========================================================================
// passC: reorder tile by bucket in LDS; flush PACKED edges
// (src in bits 0..16, dst_local in bits 17..25) to bk_pack.
// ===========================================================================
__global__ __launch_bounds__(256) void passC_kernel(
    const int* __restrict__ src, const int* __restrict__ dst,
    const int* __restrict__ g_hist, const int* __restrict__ bbase,
    unsigned* __restrict__ bk_pack)
{
    __shared__ int hist[NB];
    __shared__ int seg[NB];
    __shared__ int cur[NB];
    __shared__ int gof[NB];
    __shared__ int sc[256];
    __shared__ unsigned s_pack[TILE];
    __shared__ unsigned short s_bkt[TILE];

    int tid = threadIdx.x, tile = blockIdx.x;
    int base = tile * TILE;
    int cnt = min(TILE, N_EDGES - base);

    for (int i = tid; i < NB; i += 256) {
        hist[i] = 0;
        gof[i] = g_hist[tile * NB + i] + bbase[i];
    }
    __syncthreads();

    int es[16], ed[16];
    #pragma unroll
    for (int k = 0; k < 16; ++k) {
        int i = tid + k * 256;
        if (i < cnt) {
            es[k] = src[base + i];
            ed[k] = dst[base + i];
            atomicAdd(&hist[ed[k] >> BSHIFT], 1);
        }
    }
    __syncthreads();

    {
        int v = (tid < NB) ? hist[tid] : 0;
        sc[tid] = v;
        __syncthreads();
        for (int d = 1; d < 256; d <<= 1) {
            int t = (tid >= d) ? sc[tid - d] : 0;
            __syncthreads();
            sc[tid] += t;
            __syncthreads();
        }
        if (tid < NB) { seg[tid] = sc[tid] - v; cur[tid] = sc[tid] - v; }
    }
    __syncthreads();

    #pragma unroll
    for (int k = 0; k < 16; ++k) {
        int i = tid + k * 256;
        if (i < cnt) {
            int b = ed[k] >> BSHIFT;
            int p = atomicAdd(&cur[b], 1);
            s_pack[p] = (unsigned)es[k] | ((unsigned)(ed[k] & 511) << 17);
            s_bkt[p] = (unsigned short)b;
        }
    }
    __syncthreads();

    for (int i = tid; i < cnt; i += 256) {
        int b = s_bkt[i];
        int g = gof[b] + (i - seg[b]);
        bk_pack[g] = s_pack[i];
    }
}

// ===========================================================================
// passD: per-bucket CSR finalize from packed edges
// ===========================================================================
__global__ __launch_bounds__(512) void passD_kernel(
    const unsigned* __restrict__ bk_pack,
    const int* __restrict__ bbase, const int* __restrict__ btot,
    int* __restrict__ sorted_src, int* __restrict__ offs)
{
    __shared__ int ldeg[512];
    __shared__ int lofs[512];
    int b = blockIdx.x, tid = threadIdx.x;
    int ebase = bbase[b];
    int ecnt = btot[b];
    int nbase = b << BSHIFT;

    ldeg[tid] = 0;
    __syncthreads();
    for (int i = tid; i < ecnt; i += 512)
        atomicAdd(&ldeg[bk_pack[ebase + i] >> 17], 1);
    __syncthreads();

    int v = ldeg[tid];
    lofs[tid] = v;
    __syncthreads();
    for (int d = 1; d < 512; d <<= 1) {
        int t = (tid >= d) ? lofs[tid - d] : 0;
        __syncthreads();
        lofs[tid] += t;
        __syncthreads();
    }
    int ex = lofs[tid] - v;

    int node = nbase + tid;
    if (node < N_NODES) offs[node] = ebase + ex;

    ldeg[tid] = ex;
    __syncthreads();
    for (int i = tid; i < ecnt; i += 512) {
        unsigned pk = bk_pack[ebase + i];
        int p = atomicAdd(&ldeg[pk >> 17], 1);
        sorted_src[ebase + p] = (int)(pk & 0x1FFFFu);
    }
}

// ===========================================================================
// Gather-aggregate bf16 x rows. One node per HALF-WAVE (8 nodes/block),
// 8-deep unrolled edge loop -> 8 independent row-gathers in flight per lane.
// ===========================================================================
__global__ __launch_bounds__(256) void agg_x_kernel(
    const unsigned* __restrict__ xb,
    const int*      __restrict__ offs,
    const int*      __restrict__ ss,
    unsigned* __restrict__ acat)
{
    int node = blockIdx.x * 8 + (threadIdx.x >> 5);
    int dw   = threadIdx.x & 31;
    if (node >= N_NODES) return;
    int beg = offs[node], end = offs[node + 1];
    float2 a0 = {0.f,0.f}, a1 = {0.f,0.f}, a2 = {0.f,0.f}, a3 = {0.f,0.f};
    float2 a4 = {0.f,0.f}, a5 = {0.f,0.f}, a6 = {0.f,0.f}, a7 = {0.f,0.f};
    int i = beg;
    for (; i + 7 < end; i += 8) {
        int s0 = ss[i],     s1 = ss[i + 1], s2 = ss[i + 2], s3 = ss[i + 3];
        int s4 = ss[i + 4], s5 = ss[i + 5], s6 = ss[i + 6], s7 = ss[i + 7];
        if (dw < 25) {
            unsigned v0 = xb[s0 * 25 + dw];
            unsigned v1 = xb[s1 * 25 + dw];
            unsigned v2 = xb[s2 * 25 + dw];
            unsigned v3 = xb[s3 * 25 + dw];
            unsigned v4 = xb[s4 * 25 + dw];
            unsigned v5 = xb[s5 * 25 + dw];
            unsigned v6 = xb[s6 * 25 + dw];
            unsigned v7 = xb[s7 * 25 + dw];
            a0.x += bf_lo(v0); a0.y += bf_hi(v0);
            a1.x += bf_lo(v1); a1.y += bf_hi(v1);
            a2.x += bf_lo(v2); a2.y += bf_hi(v2);
            a3.x += bf_lo(v3); a3.y += bf_hi(v3);
            a4.x += bf_lo(v4); a4.y += bf_hi(v4);
            a5.x += bf_lo(v5); a5.y += bf_hi(v5);
            a6.x += bf_lo(v6); a6.y += bf_hi(v6);
            a7.x += bf_lo(v7); a7.y += bf_hi(v7);
        }
    }
    for (; i + 3 < end; i += 4) {
        int s0 = ss[i], s1 = ss[i + 1], s2 = ss[i + 2], s3 = ss[i + 3];
        if (dw < 25) {
            unsigned v0 = xb[s0 * 25 + dw];
            unsigned v1 = xb[s1 * 25 + dw];
            unsigned v2 = xb[s2 * 25 + dw];
            unsigned v3 = xb[s3 * 25 + dw];
            a0.x += bf_lo(v0); a0.y += bf_hi(v0);
            a1.x += bf_lo(v1); a1.y += bf_hi(v1);
            a2.x += bf_lo(v2); a2.y += bf_hi(v2);
            a3.x += bf_lo(v3); a3.y += bf_hi(v3);
        }
    }
    for (; i < end; ++i) {
        int s = ss[i];
        if (dw < 25) {
            unsigned v = xb[s * 25 + dw];
            a0.x += bf_lo(v); a0.y += bf_hi(v);
        }
    }
    if (dw < 25) {
        float inv = 1.0f / fmaxf((float)(end - beg), 1.0f);
        float sx = ((a0.x + a1.x) + (a2.x + a3.x)) + ((a4.x + a5.x) + (a6.x + a7.x));
        float sy = ((a0.y + a1.y) + (a2.y + a3.y)) + ((a4.y + a5.y) + (a6.y + a7.y));
        acat[(size_t)node * 64 + dw] = pack2(sx * inv, sy * inv);
    }
}

// ===========================================================================
// Fused MLP: h = relu(Acat @ W1cat + b1) via MFMA (swapped operands), then
// p = bf16(h@W2l), q = h@W2r + b2 via a second MFMA pass through LDS.
// ===========================================================================
__global__ __launch_bounds__(256) void fused_mlp_kernel(
    const unsigned* __restrict__ Acat,   // [N][64] dwords (128 bf16)
    const unsigned* __restrict__ Wt1g,   // [128][64] dwords
    const unsigned* __restrict__ W2tg,   // [16][64] dwords
    const float* __restrict__ b1,
    const float* __restrict__ b2,
    unsigned* __restrict__ pb,           // [N][4] dwords (8 bf16)
    float* __restrict__ q)               // [N][8]
{
    __shared__ unsigned sWt[128 * LW];
    __shared__ unsigned sW2t[16 * LW];
    __shared__ bf16_t   sH[4][16 * 136];

    int tid = threadIdx.x;
    for (int t = tid; t < 128 * 64; t += 256)
        sWt[(t >> 6) * LW + (t & 63)] = Wt1g[t];
    for (int t = tid; t < 16 * 64; t += 256)
        sW2t[(t >> 6) * LW + (t & 63)] = W2tg[t];
    __syncthreads();

    const int w    = tid >> 6;
    const int lane = tid & 63;
    const int lo   = lane & 15;
    const int g    = lane >> 4;

    float b1v[8][4];
    #pragma unroll
    for (int nt = 0; nt < 8; ++nt)
        #pragma unroll
        for (int r = 0; r < 4; ++r)
            b1v[nt][r] = b1[nt * 16 + g * 4 + r];
    float b2v[4];
    #pragma unroll
    for (int r = 0; r < 4; ++r)
        b2v[r] = (g >= 2) ? b2[(g - 2) * 4 + r] : 0.0f;

    bf16_t* myH = &sH[w][0];

    for (int tile = blockIdx.x; tile * 64 < N_NODES; tile += gridDim.x) {
        int node = tile * 64 + w * 16 + lo;
        int nclamp = min(node, N_NODES - 1);

        int4 bi[4];
        #pragma unroll
        for (int ks = 0; ks < 4; ++ks)
            bi[ks] = *((const int4*)(Acat + (size_t)nclamp * 64 + ks * 16 + g * 4));

        f32x4 acc[8];
        #pragma unroll
        for (int nt = 0; nt < 8; ++nt) acc[nt] = (f32x4)0.0f;
        #pragma unroll
        for (int nt = 0; nt < 8; ++nt) {
            #pragma unroll
            for (int ks = 0; ks < 4; ++ks) {
                int4 ai = *((const int4*)(sWt + (nt * 16 + lo) * LW + ks * 16 + g * 4));
                acc[nt] = __builtin_amdgcn_mfma_f32_16x16x32_bf16(
                    __builtin_bit_cast(bf16x8, ai),
                    __builtin_bit_cast(bf16x8, bi[ks]), acc[nt], 0, 0, 0);
            }
        }

        #pragma unroll
        for (int nt = 0; nt < 8; ++nt) {
            union { bf16_t h[4]; uint2 u; } pk;
            #pragma unroll
            for (int r = 0; r < 4; ++r)
                pk.h[r] = (bf16_t)fmaxf(acc[nt][r] + b1v[nt][r], 0.0f);
            *((uint2*)(myH + lo * 136 + nt * 16 + g * 4)) = pk.u;
        }
        __syncthreads();

        f32x4 acc2 = (f32x4)0.0f;
        #pragma unroll
        for (int ks = 0; ks < 4; ++ks) {
            int4 a2 = *((const int4*)(sW2t + lo * LW + ks * 16 + g * 4));
            int4 h2 = *((const int4*)(myH + lo * 136 + ks * 32 + g * 8));
            acc2 = __builtin_amdgcn_mfma_f32_16x16x32_bf16(
                __builtin_bit_cast(bf16x8, a2),
                __builtin_bit_cast(bf16x8, h2), acc2, 0, 0, 0);
        }

        if (node < N_NODES) {
            if (g < 2) {
                union { bf16_t h[4]; uint2 u; } pk;
                #pragma unroll
                for (int r = 0; r < 4; ++r) pk.h[r] = (bf16_t)acc2[r];
                *((uint2*)(pb + (size_t)node * 4 + g * 2)) = pk.u;
            } else {
                float4 qq;
                qq.x = acc2[0] + b2v[0];
                qq.y = acc2[1] + b2v[1];
                qq.z = acc2[2] + b2v[2];
                qq.w = acc2[3] + b2v[3];
                *((float4*)(q + (size_t)node * 8 + (g - 2) * 4)) = qq;
            }
        }
        __syncthreads();
    }
}

// ===========================================================================
// Gather-aggregate bf16 p rows + final: out = (sum p[src]) / max(deg,1) + q
// ===========================================================================
__global__ __launch_bounds__(256) void aggp_final_kernel(
    const unsigned* __restrict__ pb,   // [N][4] dwords (8 bf16)
    const float*    __restrict__ q,
    const int*      __restrict__ offs,
    const int*      __restrict__ ss,
    float* __restrict__ out)
{
    int node = blockIdx.x * 4 + (threadIdx.x >> 6);
    int lane = threadIdx.x & 63;
    int k  = lane >> 2;
    int c2 = lane & 3;
    if (node >= N_NODES) return;
    int beg = offs[node], end = offs[node + 1];
    float2 acc = make_float2(0.0f, 0.0f);
    int i = beg + k;
    int sNext = (i < end) ? ss[i] : 0;
    for (; i < end; i += 16) {
        int s = sNext;
        int i2 = i + 16;
        sNext = (i2 < end) ? ss[i2] : 0;
        unsigned v = pb[s * 4 + c2];
        acc.x += bf_lo(v);
        acc.y += bf_hi(v);
    }
    acc.x += __shfl_xor(acc.x, 4);  acc.y += __shfl_xor(acc.y, 4);
    acc.x += __shfl_xor(acc.x, 8);  acc.y += __shfl_xor(acc.y, 8);
    acc.x += __shfl_xor(acc.x, 16); acc.y += __shfl_xor(acc.y, 16);
    acc.x += __shfl_xor(acc.x, 32); acc.y += __shfl_xor(acc.y, 32);
    if (lane < 4) {
        float inv = 1.0f / fmaxf((float)(end - beg), 1.0f);
        float2 qq = ((const float2*)(q + (size_t)node * NCLS))[c2];
        ((float2*)(out + (size_t)node * NCLS))[c2] =
            make_float2(acc.x * inv + qq.x, acc.y * inv + qq.y);
    }
}

// ===========================================================================
extern "C" void kernel_launch(void* const* d_in, const int* in_sizes, int n_in,
                              void* d_out, int out_size, void* d_ws, size_t ws_size,
                              hipStream_t stream)
{
    const float* x   = (const float*)d_in[0];
    const int*   ei  = (const int*)  d_in[1];
    const float* W1l = (const float*)d_in[2];
    const float* W1r = (const float*)d_in[3];
    const float* b1  = (const float*)d_in[4];
    const float* W2l = (const float*)d_in[5];
    const float* W2r = (const float*)d_in[6];
    const float* b2  = (const float*)d_in[7];
    float* out = (float*)d_out;

    const int* src = ei;
    const int* dst = ei + N_EDGES;

    // Workspace layout (dword units; all segment sizes are multiples of 4)
    int* ws = (int*)d_ws;
    int*      offs       = ws;                                   // 100004
    int*      g_hist     = offs + (N_NODES + 4);                 // 76636
    int*      btot       = g_hist + NTILES * NB;                 // 256
    int*      bbase      = btot + 256;                           // 256
    int*      sorted_src = bbase + 256;                          // E
    unsigned* xb         = (unsigned*)(sorted_src + N_EDGES);    // N*25
    unsigned* Acat       = xb + (size_t)N_NODES * 25;            // N*64
    unsigned* Wt1g       = Acat + (size_t)N_NODES * 64;          // 8192
    unsigned* W2tg       = Wt1g + 8192;                          // 1024
    unsigned* pb         = W2tg + 1024;                          // N*4
    float*    q          = (float*)(pb + (size_t)N_NODES * 4);   // N*8
    unsigned* bk_pack    = (unsigned*)(q + (size_t)N_NODES * 8); // E

    conv_x_kernel<<<(N_NODES * 32 + 255) / 256, 256, 0, stream>>>(x, xb, Acat);
    conv_w_kernel<<<36, 256, 0, stream>>>(W1l, W1r, W2l, W2r, Wt1g, W2tg);

    // CSR build via two-level bucket sort (packed edge records)
    passA_kernel <<<NTILES, 256, 0, stream>>>(dst, g_hist);
    passB_kernel <<<NB, 512, 0, stream>>>(g_hist, btot);
    passB2_kernel<<<1, 256, 0, stream>>>(btot, bbase, offs);
    passC_kernel <<<NTILES, 256, 0, stream>>>(src, dst, g_hist, bbase, bk_pack);
    passD_kernel <<<NB, 512, 0, stream>>>(bk_pack, bbase, btot, sorted_src, offs);

    // Layer 1 aggregation (writes Acat cols 0..49)
    agg_x_kernel<<<(N_NODES + 7) / 8, 256, 0, stream>>>(xb, offs, sorted_src, Acat);

    // Fused layer1 GEMM + relu + layer2 GEMMs (h stays on-chip)
    fused_mlp_kernel<<<512, 256, 0, stream>>>(Acat, Wt1g, W2tg, b1, b2, pb, q);

    // Layer 2 aggregation + final
    aggp_final_kernel<<<(N_NODES + 3) / 4, 256, 0, stream>>>(
        (const unsigned*)pb, q, offs, sorted_src, out);
}